// Round 9
// baseline (153.686 us; speedup 1.0000x reference)
//
#include <hip/hip_runtime.h>

#define S_LEN 2048
#define DMODEL 1024
#define NH 16
#define DHD 64

typedef __attribute__((ext_vector_type(8))) short bh8;
typedef __attribute__((ext_vector_type(4))) float f32x4;
typedef __attribute__((ext_vector_type(2))) unsigned int u32x2;
typedef __attribute__((ext_vector_type(4))) unsigned int u32x4;
typedef unsigned short u16;
typedef unsigned int u32;

static __device__ __forceinline__ u16 f2bf(float f) {
    unsigned u = __builtin_bit_cast(unsigned, f);
    u += 0x7fffu + ((u >> 16) & 1u);
    return (u16)(u >> 16);
}

typedef const __attribute__((address_space(1))) void* gptr_t;
typedef __attribute__((address_space(3))) void* lptr_t;

static __device__ __forceinline__ void gll16(const void* g, void* l) {
    __builtin_amdgcn_global_load_lds((gptr_t)g, (lptr_t)l, 16, 0, 0);
}

// ---------------- convert fp32 -> bf16: weights (4x1M) + sources (3x4M) --------------
__global__ __launch_bounds__(256) void cvt_all(const float* __restrict__ WQ, const float* __restrict__ WK,
                                               const float* __restrict__ WV, const float* __restrict__ WO,
                                               const float* __restrict__ S0, const float* __restrict__ S1,
                                               const float* __restrict__ S2,
                                               u16* __restrict__ wq, u16* __restrict__ wk,
                                               u16* __restrict__ wv, u16* __restrict__ wo,
                                               u16* __restrict__ q0, u16* __restrict__ k0,
                                               u16* __restrict__ v0) {
    int bid = blockIdx.x;
    const float* s;
    u16* o;
    size_t base;
    if (bid < 2048) {
        int wi = bid >> 9;
        s = wi == 0 ? WQ : (wi == 1 ? WK : (wi == 2 ? WV : WO));
        o = wi == 0 ? wq : (wi == 1 ? wk : (wi == 2 ? wv : wo));
        base = (size_t)(bid & 511) * 2048;
    } else {
        int r = bid - 2048;
        int si = r >> 11;
        s = si == 0 ? S0 : (si == 1 ? S1 : S2);
        o = si == 0 ? q0 : (si == 1 ? k0 : v0);
        base = (size_t)(r & 2047) * 2048;
    }
    size_t i = base + (size_t)threadIdx.x * 8;
    float4 a = *(const float4*)(s + i);
    float4 b = *(const float4*)(s + i + 4);
    u32 p0 = (u32)f2bf(a.x) | ((u32)f2bf(a.y) << 16);
    u32 p1 = (u32)f2bf(a.z) | ((u32)f2bf(a.w) << 16);
    u32 p2 = (u32)f2bf(b.x) | ((u32)f2bf(b.y) << 16);
    u32 p3 = (u32)f2bf(b.z) | ((u32)f2bf(b.w) << 16);
    *(u32x4*)(o + i) = (u32x4){p0, p1, p2, p3};
}

// ---------------- GEMM body: C[M,N] = A[M,K]*B[N,K]^T + bias, 2-phase dbuf ----------------
template <int BM, int OBF, int AF32>
static __device__ __forceinline__ void gemm_body(const void* __restrict__ Ap, const u16* __restrict__ Bm,
                                                 const float* __restrict__ bias, void* __restrict__ Cv,
                                                 int N, int K, int bi, int bj, short* Al, short* Bl,
                                                 float oscale) {
    constexpr int MI = BM / 32;
    constexpr int NC = BM / 64;
    int tid = threadIdx.x, lane = tid & 63, w = tid >> 6;
    int ln = lane & 15, hi = lane >> 4;
    int wm = w >> 1, wn = w & 1;
    f32x4 acc[MI][4];
#pragma unroll
    for (int i = 0; i < MI; i++)
#pragma unroll
        for (int j = 0; j < 4; j++) acc[i][j] = (f32x4){0.f, 0.f, 0.f, 0.f};
    int nk = K >> 5;

    float4 fa[NC][2];  // in-flight f32 A (AF32 path)
    auto loadA = [&](int kt) {
#pragma unroll
        for (int c = 0; c < NC; ++c) {
            int o = c * 4096 + tid * 16;
            int row = o >> 6, e0 = (o & 63) >> 1;
            const float* src = (const float*)Ap + (size_t)(bi * BM + row) * K + kt * 32 + e0;
            fa[c][0] = *(const float4*)src;
            fa[c][1] = *(const float4*)(src + 4);
        }
    };
    auto writeA = [&](int buf) {
#pragma unroll
        for (int c = 0; c < NC; ++c) {
            int o = c * 4096 + tid * 16;
            u32 w0 = (u32)f2bf(fa[c][0].x) | ((u32)f2bf(fa[c][0].y) << 16);
            u32 w1 = (u32)f2bf(fa[c][0].z) | ((u32)f2bf(fa[c][0].w) << 16);
            u32 w2 = (u32)f2bf(fa[c][1].x) | ((u32)f2bf(fa[c][1].y) << 16);
            u32 w3 = (u32)f2bf(fa[c][1].z) | ((u32)f2bf(fa[c][1].w) << 16);
            *(u32x4*)((char*)(Al + buf * (BM * 32)) + o) = (u32x4){w0, w1, w2, w3};
        }
    };
    auto stageA_lds = [&](int buf, int kt) {
#pragma unroll
        for (int c = 0; c < NC; ++c) {
            int o = c * 4096 + tid * 16;
            int row = o >> 6, col = (o & 63) >> 1;
            gll16((const u16*)Ap + (size_t)(bi * BM + row) * K + kt * 32 + col,
                  (char*)(Al + buf * (BM * 32)) + o);
        }
    };
    auto stageB = [&](int buf, int kt) {
#pragma unroll
        for (int c = 0; c < 2; ++c) {
            int o = c * 4096 + tid * 16;
            int row = o >> 6, col = (o & 63) >> 1;
            gll16(Bm + (size_t)(bj * 128 + row) * K + kt * 32 + col, (char*)(Bl + buf * 4096) + o);
        }
    };

    if constexpr (AF32) { loadA(0); writeA(0); } else { stageA_lds(0, 0); }
    stageB(0, 0);
    __syncthreads();
    int cur = 0;
    for (int kt = 0; kt < nk; ++kt) {
        bool pre = (kt + 1 < nk);
        if (pre) {
            if constexpr (AF32) loadA(kt + 1); else stageA_lds(cur ^ 1, kt + 1);
            stageB(cur ^ 1, kt + 1);
        }
        bh8 av[MI], bv[4];
#pragma unroll
        for (int i = 0; i < MI; i++) av[i] = *(const bh8*)&Al[cur * (BM * 32) + (wm * (BM / 2) + i * 16 + ln) * 32 + hi * 8];
#pragma unroll
        for (int j = 0; j < 4; j++) bv[j] = *(const bh8*)&Bl[cur * 4096 + (wn * 64 + j * 16 + ln) * 32 + hi * 8];
#pragma unroll
        for (int i = 0; i < MI; i++)
#pragma unroll
            for (int j = 0; j < 4; j++)
                acc[i][j] = __builtin_amdgcn_mfma_f32_16x16x32_bf16(av[i], bv[j], acc[i][j], 0, 0, 0);
        if constexpr (AF32) { if (pre) writeA(cur ^ 1); }
        __syncthreads();
        cur ^= 1;
    }
    if constexpr (OBF == 2) {
        // V projection: write C^T into VT[b,h,d,s] via LDS transpose (reuses Al+Bl = 32KB)
#pragma unroll
        for (int j = 0; j < 4; j++) {
            int col = wn * 64 + j * 16 + ln;  // local d_model col 0..127
            float bvs = bias[bj * 128 + col];
#pragma unroll
            for (int i = 0; i < MI; i++) {
                int row0 = wm * (BM / 2) + i * 16 + hi * 4;  // local s row
                u32 p01 = (u32)f2bf(acc[i][j][0] + bvs) | ((u32)f2bf(acc[i][j][1] + bvs) << 16);
                u32 p23 = (u32)f2bf(acc[i][j][2] + bvs) | ((u32)f2bf(acc[i][j][3] + bvs) << 16);
                int idx = col * 128 + (row0 ^ ((col & 7) << 3));
                *(u32x2*)&Al[idx] = (u32x2){p01, p23};
            }
        }
        __syncthreads();
        int b = bi >> 4;
        int sbase = (bi & 15) * 128;
#pragma unroll
        for (int it = 0; it < 8; ++it) {
            int idx = it * 256 + tid;
            int dcol = idx >> 4;           // 0..127
            int sl = (idx & 15) * 8;       // 0..120
            bh8 v = *(const bh8*)&Al[dcol * 128 + (sl ^ ((dcol & 7) << 3))];
            int h = bj * 2 + (dcol >> 6), d = dcol & 63;
            *(bh8*)((u16*)Cv + ((size_t)((b * 16 + h) * 64 + d)) * 2048 + sbase + sl) = v;
        }
        return;
    }
#pragma unroll
    for (int j = 0; j < 4; j++) {
        int col = bj * 128 + wn * 64 + j * 16 + ln;
        float bvs = bias[col];
#pragma unroll
        for (int i = 0; i < MI; i++) {
            int row0 = bi * BM + wm * (BM / 2) + i * 16 + hi * 4;
#pragma unroll
            for (int rr = 0; rr < 4; rr++) {
                if (OBF) {
                    float v = (acc[i][j][rr] + bvs) * oscale;  // Q-proj folds softmax scale here
                    ((u16*)Cv)[(size_t)(row0 + rr) * N + col] = f2bf(v);
                } else {
                    ((float*)Cv)[(size_t)(row0 + rr) * N + col] = acc[i][j][rr] + bvs;
                }
            }
        }
    }
}

// fused QKV projections, A pre-converted to bf16: grid 768 (XCD-swizzled); z==2 (V) writes VT
__global__ __launch_bounds__(256, 3) void gemm_qkv(const u16* __restrict__ A0, const u16* __restrict__ A1,
                                                   const u16* __restrict__ A2, const u16* __restrict__ B0,
                                                   const u16* __restrict__ B1, const u16* __restrict__ B2,
                                                   const float* __restrict__ c0, const float* __restrict__ c1,
                                                   const float* __restrict__ c2, u16* __restrict__ C0,
                                                   u16* __restrict__ C1, u16* __restrict__ VT) {
    __shared__ short SH[16384];  // 32KB: Al(16KB) + Bl(16KB); reused whole for V transpose
    short* Al = SH;
    short* Bl = SH + 8192;
    int bid = blockIdx.x;
    int swz = (bid & 7) * 96 + (bid >> 3);
    int z = swz >> 8, t = swz & 255;
    if (z == 2) {
        gemm_body<128, 2, 0>(A2, B2, c2, VT, 1024, 1024, t >> 3, t & 7, Al, Bl, 1.0f);
    } else if (z == 0) {
        gemm_body<128, 1, 0>(A0, B0, c0, C0, 1024, 1024, t >> 3, t & 7, Al, Bl, 0.18033688f);
    } else {
        gemm_body<128, 1, 0>(A1, B1, c1, C1, 1024, 1024, t >> 3, t & 7, Al, Bl, 1.0f);
    }
}

__global__ __launch_bounds__(256) void gemm_o(const u16* __restrict__ A, const u16* __restrict__ Bm,
                                              const float* __restrict__ bias, float* __restrict__ C) {
    __shared__ short Al[2 * 64 * 32];
    __shared__ short Bl[2 * 128 * 32];
    int bid = blockIdx.x;
    int swz = (bid & 7) * 64 + (bid >> 3);
    gemm_body<64, 0, 0>(A, Bm, bias, C, 1024, 1024, swz >> 3, swz & 7, Al, Bl, 1.0f);
}

// ------- flash attention (causal): BARRIER-FREE, K/V from L2 to registers (R8) -----------
// Ledger R0-R7: per-CU throughput pinned at ~3000 cy/kv-tile across 4-16 waves/CU, all
// pipelining/priority/DS-traffic/split variants. No pipe saturated -> block-lockstep phase
// serialization (per-tile __syncthreads forced by cooperative LDS staging makes all waves
// hit MFMA/VALU/DS phases together; pipes used serially). R8 removes the barrier entirely:
// K/V fragments loaded per-wave from global (L2-resident: 2MB K+VT per XCD, guide m169:
// staging L2-fitting data is pure overhead) straight into MFMA registers; P in wave-private
// LDS (in-order DS, no barrier). Waves fully independent -> natural de-phasing -> cross-wave
// pipe overlap (m114). 32 q-rows/wave keeps L2 reads ~560MB (~20 TB/s < 34.5 ceiling).
// Single-buffered K/V regs: loadK(t+1) issued after QK(t), loadV(t+1) after PV(t) -> ~500cy
// compute hides L2 latency. Grid 1024 x 128thr (2 waves x 32q = QBLK 64), LPT qt-desc,
// bh XCD-pinned.
template <int PLO, int PHI>
static __device__ __forceinline__ void attn_core(const u16* __restrict__ Qp, const u16* __restrict__ Kp,
                                                 const u16* __restrict__ VT, u16* __restrict__ Ctx,
                                                 short* Pw, int b, int h, int bh, int qt, int w, int lane) {
    int ln = lane & 15, hi = lane >> 4;
    __builtin_amdgcn_s_setprio(PLO);
    int nt = qt + 1;                       // causal kv tiles (KVBLK=QBLK=64, aligned)
    int qg0 = (qt << 6) + w * 32 + ln;     // q-group 0 row; group 1 = qg0 + 16
    const bh8* qr0 = (const bh8*)(Qp + ((size_t)(b * S_LEN + qg0)) * DMODEL + h * DHD);
    const bh8* qr1 = (const bh8*)(Qp + ((size_t)(b * S_LEN + qg0 + 16)) * DMODEL + h * DHD);
    bh8 qf[2][2];
    qf[0][0] = qr0[hi]; qf[0][1] = qr0[4 + hi];
    qf[1][0] = qr1[hi]; qf[1][1] = qr1[4 + hi];

    // per-lane fragment base pointers (mirror the LDS-read fragment math, un-swizzled)
    const u16* kp0 = Kp + ((size_t)(b * S_LEN + ln)) * DMODEL + h * DHD + hi * 8;
    const u16* vp0 = VT + ((size_t)(bh * DHD + ln)) * S_LEN + hi * 8;

    bh8 kr[4][2], vr[4][2];
    auto loadK = [&](int kt) {
        const u16* p = kp0 + (size_t)kt * 64 * DMODEL;
#pragma unroll
        for (int ks = 0; ks < 4; ++ks) {
            kr[ks][0] = *(const bh8*)(p + (size_t)ks * 16 * DMODEL);
            kr[ks][1] = *(const bh8*)(p + (size_t)ks * 16 * DMODEL + 32);
        }
    };
    auto loadV = [&](int kt) {
        const u16* p = vp0 + kt * 64;
#pragma unroll
        for (int ds = 0; ds < 4; ++ds) {
            vr[ds][0] = *(const bh8*)(p + (size_t)ds * 16 * S_LEN);
            vr[ds][1] = *(const bh8*)(p + (size_t)ds * 16 * S_LEN + 32);
        }
    };

    f32x4 ctxa[2][4];
    float ls[2] = {0.f, 0.f};
#pragma unroll
    for (int g = 0; g < 2; g++)
#pragma unroll
        for (int i = 0; i < 4; i++) ctxa[g][i] = (f32x4){0.f, 0.f, 0.f, 0.f};

    loadK(0);
    loadV(0);
    for (int kt = 0; kt < nt; ++kt) {
        bool pre = (kt + 1 < nt);
        f32x4 sc[2][4];
#pragma unroll
        for (int g = 0; g < 2; g++)
#pragma unroll
            for (int ks = 0; ks < 4; ++ks) sc[g][ks] = (f32x4){0.f, 0.f, 0.f, 0.f};
        __builtin_amdgcn_s_setprio(PHI);
#pragma unroll
        for (int dwin = 0; dwin < 2; ++dwin) {
#pragma unroll
            for (int ks = 0; ks < 4; ++ks) {
                sc[0][ks] = __builtin_amdgcn_mfma_f32_16x16x32_bf16(kr[ks][dwin], qf[0][dwin], sc[0][ks], 0, 0, 0);
                sc[1][ks] = __builtin_amdgcn_mfma_f32_16x16x32_bf16(kr[ks][dwin], qf[1][dwin], sc[1][ks], 0, 0, 0);
            }
        }
        __builtin_amdgcn_s_setprio(PLO);
        if (pre) loadK(kt + 1);            // K regs dead after QK; L2 latency hides under SM+PV
        if (kt == nt - 1) {                // only the last tile crosses the causal diagonal
#pragma unroll
            for (int g = 0; g < 2; g++) {
                int qgq = qg0 + g * 16;
#pragma unroll
                for (int ks = 0; ks < 4; ++ks)
#pragma unroll
                    for (int rr = 0; rr < 4; ++rr) {
                        int kg = kt * 64 + ks * 16 + hi * 4 + rr;
                        sc[g][ks][rr] = (kg <= qgq) ? sc[g][ks][rr] : -1e30f;
                    }
            }
        }
        // per-q-group: SM(g) -> wave-private P -> PV(g); no cross-wave sync anywhere
#pragma unroll
        for (int g = 0; g < 2; g++) {
#pragma unroll
            for (int ks = 0; ks < 4; ++ks) {
                float p0 = __builtin_amdgcn_exp2f(sc[g][ks][0]);
                float p1 = __builtin_amdgcn_exp2f(sc[g][ks][1]);
                float p2 = __builtin_amdgcn_exp2f(sc[g][ks][2]);
                float p3 = __builtin_amdgcn_exp2f(sc[g][ks][3]);
                ls[g] += (p0 + p1) + (p2 + p3);   // l from f32 P (pre-truncation)
                u32 u0 = __builtin_bit_cast(u32, p0);
                u32 u1 = __builtin_bit_cast(u32, p1);
                u32 u2 = __builtin_bit_cast(u32, p2);
                u32 u3 = __builtin_bit_cast(u32, p3);
                u32 a01 = (u0 >> 16) | (u1 & 0xffff0000u);   // truncating bf16 pack
                u32 a23 = (u2 >> 16) | (u3 & 0xffff0000u);
                int kloc = ks * 16 + hi * 4;
                *(u32x2*)&Pw[ln * 64 + (kloc ^ ((ln & 7) << 3))] = (u32x2){a01, a23};
            }
            __builtin_amdgcn_s_setprio(PHI);
#pragma unroll
            for (int kw = 0; kw < 2; ++kw) {
                bh8 pf = *(const bh8*)&Pw[ln * 64 + ((kw * 32 + hi * 8) ^ ((ln & 7) << 3))];
#pragma unroll
                for (int ds = 0; ds < 4; ++ds)
                    ctxa[g][ds] = __builtin_amdgcn_mfma_f32_16x16x32_bf16(vr[ds][kw], pf, ctxa[g][ds], 0, 0, 0);
            }
            __builtin_amdgcn_s_setprio(PLO);
        }
        if (pre) loadV(kt + 1);            // V regs dead after PV g1; latency hides under QK(t+1)+SM
    }
    // full row-sum l: combine the 4 hi-lanes of each q column
#pragma unroll
    for (int g = 0; g < 2; g++) {
        ls[g] += __shfl_xor(ls[g], 16);
        ls[g] += __shfl_xor(ls[g], 32);
    }
    __builtin_amdgcn_s_setprio(0);
#pragma unroll
    for (int g = 0; g < 2; g++) {
        float inv = 1.f / ls[g];
        u16* cp = Ctx + ((size_t)(b * S_LEN + qg0 + g * 16)) * DMODEL + h * DHD;
#pragma unroll
        for (int ds = 0; ds < 4; ++ds) {
            ushort4 st;
            st.x = f2bf(ctxa[g][ds][0] * inv);
            st.y = f2bf(ctxa[g][ds][1] * inv);
            st.z = f2bf(ctxa[g][ds][2] * inv);
            st.w = f2bf(ctxa[g][ds][3] * inv);
            *(ushort4*)(cp + ds * 16 + hi * 4) = st;
        }
    }
}

__global__ __launch_bounds__(128, 2) void attn_fwd(const u16* __restrict__ Qp, const u16* __restrict__ Kp,
                                                   const u16* __restrict__ VT, u16* __restrict__ Ctx) {
    __shared__ short Pl[2][1024];          // wave-private 16x64 P buffers (4KB total)
    int tid = threadIdx.x, lane = tid & 63, w = tid >> 6;
    int bid = blockIdx.x;
    // LPT: qt descending, XCD-interleaved; bh pinned to XCD (K/V L2 residency)
    int xcd = bid & 7;
    int bh = xcd * 4 + ((bid >> 3) & 3);
    int qt = 31 - (bid >> 5);              // 0..31 (QBLK=64)
    int b = bh >> 4, h = bh & 15;
    if (qt >= 16)
        attn_core<2, 3>(Qp, Kp, VT, Ctx, &Pl[w][0], b, h, bh, qt, w, lane);
    else
        attn_core<0, 1>(Qp, Kp, VT, Ctx, &Pl[w][0], b, h, bh, qt, w, lane);
}

// ---------------- residual + LayerNorm ----------------
__global__ __launch_bounds__(256) void ln_res(const float* __restrict__ Xres, const float* __restrict__ Y,
                                              const float* __restrict__ gamma, const float* __restrict__ beta,
                                              float* __restrict__ out) {
    int row = blockIdx.x, tid = threadIdx.x;
    const float4* xr = (const float4*)(Xres + (size_t)row * DMODEL);
    const float4* yr = (const float4*)(Y + (size_t)row * DMODEL);
    float4 a = xr[tid], bq = yr[tid];
    float x0 = a.x + bq.x, x1 = a.y + bq.y, x2 = a.z + bq.z, x3 = a.w + bq.w;
    float s1 = x0 + x1 + x2 + x3;
    float s2 = x0 * x0 + x1 * x1 + x2 * x2 + x3 * x3;
#pragma unroll
    for (int off = 32; off > 0; off >>= 1) {
        s1 += __shfl_xor(s1, off);
        s2 += __shfl_xor(s2, off);
    }
    __shared__ float r1[4], r2[4];
    int wv = tid >> 6;
    if ((tid & 63) == 0) { r1[wv] = s1; r2[wv] = s2; }
    __syncthreads();
    s1 = r1[0] + r1[1] + r1[2] + r1[3];
    s2 = r2[0] + r2[1] + r2[2] + r2[3];
    float mu = s1 * (1.0f / 1024.0f);
    float var = s2 * (1.0f / 1024.0f) - mu * mu;
    float rstd = rsqrtf(var + 1e-5f);
    const float4* g4 = (const float4*)gamma;
    const float4* b4 = (const float4*)beta;
    float4 g = g4[tid], bb = b4[tid];
    float4 res;
    res.x = (x0 - mu) * rstd * g.x + bb.x;
    res.y = (x1 - mu) * rstd * g.y + bb.y;
    res.z = (x2 - mu) * rstd * g.z + bb.z;
    res.w = (x3 - mu) * rstd * g.w + bb.w;
    *((float4*)(out + (size_t)row * DMODEL) + tid) = res;
}

extern "C" void kernel_launch(void* const* d_in, const int* in_sizes, int n_in,
                              void* d_out, int out_size, void* d_ws, size_t ws_size,
                              hipStream_t stream) {
    const float* Qs = (const float*)d_in[0];
    const float* Ks = (const float*)d_in[1];
    const float* Vs = (const float*)d_in[2];
    const float* WQ = (const float*)d_in[5];
    const float* bQ = (const float*)d_in[6];
    const float* WK = (const float*)d_in[7];
    const float* bK = (const float*)d_in[8];
    const float* WV = (const float*)d_in[9];
    const float* bV = (const float*)d_in[10];
    const float* WO = (const float*)d_in[11];
    const float* bO = (const float*)d_in[12];
    const float* gamma = (const float*)d_in[13];
    const float* beta = (const float*)d_in[14];

    const size_t MB = 1u << 20;
    char* w8 = (char*)d_ws;
    u16* Qb  = (u16*)(w8 + 0 * MB);   // bf16 sources (8MB each)
    u16* Kb  = (u16*)(w8 + 8 * MB);
    u16* Vb  = (u16*)(w8 + 16 * MB);
    u16* WQb = (u16*)(w8 + 24 * MB);
    u16* WKb = (u16*)(w8 + 26 * MB);
    u16* WVb = (u16*)(w8 + 28 * MB);
    u16* WOb = (u16*)(w8 + 30 * MB);
    u16* Qp  = (u16*)(w8 + 32 * MB);
    u16* Kp  = (u16*)(w8 + 40 * MB);
    u16* VTb = (u16*)(w8 + 56 * MB);
    u16* Ctx = (u16*)(w8 + 64 * MB);
    float* Y2 = (float*)(w8 + 72 * MB);

    cvt_all<<<8192, 256, 0, stream>>>(WQ, WK, WV, WO, Qs, Ks, Vs, WQb, WKb, WVb, WOb, Qb, Kb, Vb);
    gemm_qkv<<<768, 256, 0, stream>>>(Qb, Kb, Vb, WQb, WKb, WVb, bQ, bK, bV, Qp, Kp, VTb);
    attn_fwd<<<1024, 128, 0, stream>>>(Qp, Kp, VTb, Ctx);
    gemm_o<<<512, 256, 0, stream>>>(Ctx, WOb, bO, Y2);
    ln_res<<<4096, 256, 0, stream>>>(Qs, Y2, gamma, beta, (float*)d_out);
}

// Round 10
// 113.637 us; speedup vs baseline: 1.3524x; 1.3524x over previous
//
#include <hip/hip_runtime.h>

#define S_LEN 2048
#define DMODEL 1024
#define NH 16
#define DHD 64

typedef __attribute__((ext_vector_type(8))) short bh8;
typedef __attribute__((ext_vector_type(4))) float f32x4;
typedef __attribute__((ext_vector_type(2))) unsigned int u32x2;
typedef __attribute__((ext_vector_type(4))) unsigned int u32x4;
typedef unsigned short u16;
typedef unsigned int u32;

static __device__ __forceinline__ u16 f2bf(float f) {
    unsigned u = __builtin_bit_cast(unsigned, f);
    u += 0x7fffu + ((u >> 16) & 1u);
    return (u16)(u >> 16);
}

typedef const __attribute__((address_space(1))) void* gptr_t;
typedef __attribute__((address_space(3))) void* lptr_t;

static __device__ __forceinline__ void gll16(const void* g, void* l) {
    __builtin_amdgcn_global_load_lds((gptr_t)g, (lptr_t)l, 16, 0, 0);
}

// ---------------- convert fp32 -> bf16: weights (4x1M) + sources (3x4M) --------------
__global__ __launch_bounds__(256) void cvt_all(const float* __restrict__ WQ, const float* __restrict__ WK,
                                               const float* __restrict__ WV, const float* __restrict__ WO,
                                               const float* __restrict__ S0, const float* __restrict__ S1,
                                               const float* __restrict__ S2,
                                               u16* __restrict__ wq, u16* __restrict__ wk,
                                               u16* __restrict__ wv, u16* __restrict__ wo,
                                               u16* __restrict__ q0, u16* __restrict__ k0,
                                               u16* __restrict__ v0) {
    int bid = blockIdx.x;
    const float* s;
    u16* o;
    size_t base;
    if (bid < 2048) {
        int wi = bid >> 9;
        s = wi == 0 ? WQ : (wi == 1 ? WK : (wi == 2 ? WV : WO));
        o = wi == 0 ? wq : (wi == 1 ? wk : (wi == 2 ? wv : wo));
        base = (size_t)(bid & 511) * 2048;
    } else {
        int r = bid - 2048;
        int si = r >> 11;
        s = si == 0 ? S0 : (si == 1 ? S1 : S2);
        o = si == 0 ? q0 : (si == 1 ? k0 : v0);
        base = (size_t)(r & 2047) * 2048;
    }
    size_t i = base + (size_t)threadIdx.x * 8;
    float4 a = *(const float4*)(s + i);
    float4 b = *(const float4*)(s + i + 4);
    u32 p0 = (u32)f2bf(a.x) | ((u32)f2bf(a.y) << 16);
    u32 p1 = (u32)f2bf(a.z) | ((u32)f2bf(a.w) << 16);
    u32 p2 = (u32)f2bf(b.x) | ((u32)f2bf(b.y) << 16);
    u32 p3 = (u32)f2bf(b.z) | ((u32)f2bf(b.w) << 16);
    *(u32x4*)(o + i) = (u32x4){p0, p1, p2, p3};
}

// ---------------- GEMM body: C[M,N] = A[M,K]*B[N,K]^T + bias, 2-phase dbuf ----------------
template <int BM, int OBF, int AF32>
static __device__ __forceinline__ void gemm_body(const void* __restrict__ Ap, const u16* __restrict__ Bm,
                                                 const float* __restrict__ bias, void* __restrict__ Cv,
                                                 int N, int K, int bi, int bj, short* Al, short* Bl,
                                                 float oscale) {
    constexpr int MI = BM / 32;
    constexpr int NC = BM / 64;
    int tid = threadIdx.x, lane = tid & 63, w = tid >> 6;
    int ln = lane & 15, hi = lane >> 4;
    int wm = w >> 1, wn = w & 1;
    f32x4 acc[MI][4];
#pragma unroll
    for (int i = 0; i < MI; i++)
#pragma unroll
        for (int j = 0; j < 4; j++) acc[i][j] = (f32x4){0.f, 0.f, 0.f, 0.f};
    int nk = K >> 5;

    float4 fa[NC][2];  // in-flight f32 A (AF32 path)
    auto loadA = [&](int kt) {
#pragma unroll
        for (int c = 0; c < NC; ++c) {
            int o = c * 4096 + tid * 16;
            int row = o >> 6, e0 = (o & 63) >> 1;
            const float* src = (const float*)Ap + (size_t)(bi * BM + row) * K + kt * 32 + e0;
            fa[c][0] = *(const float4*)src;
            fa[c][1] = *(const float4*)(src + 4);
        }
    };
    auto writeA = [&](int buf) {
#pragma unroll
        for (int c = 0; c < NC; ++c) {
            int o = c * 4096 + tid * 16;
            u32 w0 = (u32)f2bf(fa[c][0].x) | ((u32)f2bf(fa[c][0].y) << 16);
            u32 w1 = (u32)f2bf(fa[c][0].z) | ((u32)f2bf(fa[c][0].w) << 16);
            u32 w2 = (u32)f2bf(fa[c][1].x) | ((u32)f2bf(fa[c][1].y) << 16);
            u32 w3 = (u32)f2bf(fa[c][1].z) | ((u32)f2bf(fa[c][1].w) << 16);
            *(u32x4*)((char*)(Al + buf * (BM * 32)) + o) = (u32x4){w0, w1, w2, w3};
        }
    };
    auto stageA_lds = [&](int buf, int kt) {
#pragma unroll
        for (int c = 0; c < NC; ++c) {
            int o = c * 4096 + tid * 16;
            int row = o >> 6, col = (o & 63) >> 1;
            gll16((const u16*)Ap + (size_t)(bi * BM + row) * K + kt * 32 + col,
                  (char*)(Al + buf * (BM * 32)) + o);
        }
    };
    auto stageB = [&](int buf, int kt) {
#pragma unroll
        for (int c = 0; c < 2; ++c) {
            int o = c * 4096 + tid * 16;
            int row = o >> 6, col = (o & 63) >> 1;
            gll16(Bm + (size_t)(bj * 128 + row) * K + kt * 32 + col, (char*)(Bl + buf * 4096) + o);
        }
    };

    if constexpr (AF32) { loadA(0); writeA(0); } else { stageA_lds(0, 0); }
    stageB(0, 0);
    __syncthreads();
    int cur = 0;
    for (int kt = 0; kt < nk; ++kt) {
        bool pre = (kt + 1 < nk);
        if (pre) {
            if constexpr (AF32) loadA(kt + 1); else stageA_lds(cur ^ 1, kt + 1);
            stageB(cur ^ 1, kt + 1);
        }
        bh8 av[MI], bv[4];
#pragma unroll
        for (int i = 0; i < MI; i++) av[i] = *(const bh8*)&Al[cur * (BM * 32) + (wm * (BM / 2) + i * 16 + ln) * 32 + hi * 8];
#pragma unroll
        for (int j = 0; j < 4; j++) bv[j] = *(const bh8*)&Bl[cur * 4096 + (wn * 64 + j * 16 + ln) * 32 + hi * 8];
#pragma unroll
        for (int i = 0; i < MI; i++)
#pragma unroll
            for (int j = 0; j < 4; j++)
                acc[i][j] = __builtin_amdgcn_mfma_f32_16x16x32_bf16(av[i], bv[j], acc[i][j], 0, 0, 0);
        if constexpr (AF32) { if (pre) writeA(cur ^ 1); }
        __syncthreads();
        cur ^= 1;
    }
    if constexpr (OBF == 2) {
        // V projection: write C^T into VT[b,h,d,s] via LDS transpose (reuses Al+Bl = 32KB)
#pragma unroll
        for (int j = 0; j < 4; j++) {
            int col = wn * 64 + j * 16 + ln;  // local d_model col 0..127
            float bvs = bias[bj * 128 + col];
#pragma unroll
            for (int i = 0; i < MI; i++) {
                int row0 = wm * (BM / 2) + i * 16 + hi * 4;  // local s row
                u32 p01 = (u32)f2bf(acc[i][j][0] + bvs) | ((u32)f2bf(acc[i][j][1] + bvs) << 16);
                u32 p23 = (u32)f2bf(acc[i][j][2] + bvs) | ((u32)f2bf(acc[i][j][3] + bvs) << 16);
                int idx = col * 128 + (row0 ^ ((col & 7) << 3));
                *(u32x2*)&Al[idx] = (u32x2){p01, p23};
            }
        }
        __syncthreads();
        int b = bi >> 4;
        int sbase = (bi & 15) * 128;
#pragma unroll
        for (int it = 0; it < 8; ++it) {
            int idx = it * 256 + tid;
            int dcol = idx >> 4;           // 0..127
            int sl = (idx & 15) * 8;       // 0..120
            bh8 v = *(const bh8*)&Al[dcol * 128 + (sl ^ ((dcol & 7) << 3))];
            int h = bj * 2 + (dcol >> 6), d = dcol & 63;
            *(bh8*)((u16*)Cv + ((size_t)((b * 16 + h) * 64 + d)) * 2048 + sbase + sl) = v;
        }
        return;
    }
#pragma unroll
    for (int j = 0; j < 4; j++) {
        int col = bj * 128 + wn * 64 + j * 16 + ln;
        float bvs = bias[col];
#pragma unroll
        for (int i = 0; i < MI; i++) {
            int row0 = bi * BM + wm * (BM / 2) + i * 16 + hi * 4;
#pragma unroll
            for (int rr = 0; rr < 4; rr++) {
                if (OBF) {
                    float v = (acc[i][j][rr] + bvs) * oscale;  // Q-proj folds softmax scale here
                    ((u16*)Cv)[(size_t)(row0 + rr) * N + col] = f2bf(v);
                } else {
                    ((float*)Cv)[(size_t)(row0 + rr) * N + col] = acc[i][j][rr] + bvs;
                }
            }
        }
    }
}

// fused QKV projections, A pre-converted to bf16: grid 768 (XCD-swizzled); z==2 (V) writes VT
__global__ __launch_bounds__(256, 3) void gemm_qkv(const u16* __restrict__ A0, const u16* __restrict__ A1,
                                                   const u16* __restrict__ A2, const u16* __restrict__ B0,
                                                   const u16* __restrict__ B1, const u16* __restrict__ B2,
                                                   const float* __restrict__ c0, const float* __restrict__ c1,
                                                   const float* __restrict__ c2, u16* __restrict__ C0,
                                                   u16* __restrict__ C1, u16* __restrict__ VT) {
    __shared__ short SH[16384];  // 32KB: Al(16KB) + Bl(16KB); reused whole for V transpose
    short* Al = SH;
    short* Bl = SH + 8192;
    int bid = blockIdx.x;
    int swz = (bid & 7) * 96 + (bid >> 3);
    int z = swz >> 8, t = swz & 255;
    if (z == 2) {
        gemm_body<128, 2, 0>(A2, B2, c2, VT, 1024, 1024, t >> 3, t & 7, Al, Bl, 1.0f);
    } else if (z == 0) {
        gemm_body<128, 1, 0>(A0, B0, c0, C0, 1024, 1024, t >> 3, t & 7, Al, Bl, 0.18033688f);
    } else {
        gemm_body<128, 1, 0>(A1, B1, c1, C1, 1024, 1024, t >> 3, t & 7, Al, Bl, 1.0f);
    }
}

__global__ __launch_bounds__(256) void gemm_o(const u16* __restrict__ A, const u16* __restrict__ Bm,
                                              const float* __restrict__ bias, float* __restrict__ C) {
    __shared__ short Al[2 * 64 * 32];
    __shared__ short Bl[2 * 128 * 32];
    int bid = blockIdx.x;
    int swz = (bid & 7) * 64 + (bid >> 3);
    gemm_body<64, 0, 0>(A, Bm, bias, C, 1024, 1024, swz >> 3, swz & 7, Al, Bl, 1.0f);
}

// ------- flash attention (causal): INTRA-BLOCK SPLIT-KV, LDS reduction (R6 = best) -------
// Proven 112.9us configuration: waves 0-3 take kv tiles [0,qt], waves 4-7 take
// [qt+1,2qt+1] (both exactly qt+1 tiles -> uniform loop/barriers), each wave 32 q-rows.
// Fixed-base softmax => partials additive; epilogue: grp1 writes ctx/l to LDS, barrier,
// grp0 combines+normalizes+writes. Critical chain 32 -> 16 tiles. 1 block/CU.
// R9 isolated micro-change: l accumulated on VALU during exp2 (f32, pre-truncation) +
// 2 end shfl_xor, replacing the two per-tile ones-MFMAs (-2 of 26 MFMA/step; VALU has
// headroom). Everything else byte-identical to the 112.9 kernel.
template <int PLO, int PHI>
static __device__ __forceinline__ void attn_core(const u16* __restrict__ Qp, const u16* __restrict__ Kp,
                                                 const u16* __restrict__ VT, u16* __restrict__ Ctx,
                                                 short* Klb, short* Vlb, short* Pw, float* Csh, float* Ls,
                                                 int b, int h, int bh, int qt, int tid) {
    int lane = tid & 63, w = tid >> 6;       // w 0..7
    int grp = w >> 2;                        // kv chunk group
    int qsub = w & 3;                        // q-slot within group (32 rows each)
    int tgl = tid & 255;                     // thread id within group
    int ln = lane & 15, hi = lane >> 4;
    __builtin_amdgcn_s_setprio(PLO);

    // per-group staging: Klb/Vlb point at this group's dbuf area (2 x 8KB each)
    auto stage_kv = [&](int buf, int kt) {
#pragma unroll
        for (int c = 0; c < 2; ++c) {
            int o = c * 4096 + tgl * 16;     // 256 threads x 2 x 16B = 8KB per matrix
            int rr = o >> 7;
            int slot = (o >> 4) & 7;
            gll16(Kp + ((size_t)(b * S_LEN + kt * 64 + rr)) * DMODEL + h * DHD + ((slot ^ (rr & 7)) << 3),
                  (char*)(Klb + buf * 4096) + o);
            gll16(VT + ((size_t)(bh * DHD + rr)) * S_LEN + kt * 64 + ((slot ^ (rr & 7)) << 3),
                  (char*)(Vlb + buf * 4096) + o);
        }
    };

    int nh = qt + 1;                         // tiles per group
    int nt = 2 * qt + 2;                     // total causal kv tiles
    int kbase = grp * nh;
    int qg0 = (qt << 7) + qsub * 32 + ln;    // q-group 0 row; group 1 = qg0 + 16
    const bh8* qr0 = (const bh8*)(Qp + ((size_t)(b * S_LEN + qg0)) * DMODEL + h * DHD);
    const bh8* qr1 = (const bh8*)(Qp + ((size_t)(b * S_LEN + qg0 + 16)) * DMODEL + h * DHD);
    bh8 qf[2][2];
    qf[0][0] = qr0[hi]; qf[0][1] = qr0[4 + hi];
    qf[1][0] = qr1[hi]; qf[1][1] = qr1[4 + hi];
    f32x4 ctxa[2][4];
    float ls[2] = {0.f, 0.f};
#pragma unroll
    for (int g = 0; g < 2; g++)
#pragma unroll
        for (int i = 0; i < 4; i++) ctxa[g][i] = (f32x4){0.f, 0.f, 0.f, 0.f};
    stage_kv(0, kbase);
    __syncthreads();
    int cur = 0;
    for (int i = 0; i < nh; ++i) {
        int kt = kbase + i;
        if (i + 1 < nh) stage_kv(cur ^ 1, kt + 1);
        f32x4 sc[2][4];
#pragma unroll
        for (int g = 0; g < 2; g++)
#pragma unroll
            for (int ks = 0; ks < 4; ++ks) sc[g][ks] = (f32x4){0.f, 0.f, 0.f, 0.f};
        __builtin_amdgcn_s_setprio(PHI);
#pragma unroll
        for (int dwin = 0; dwin < 2; ++dwin) {
#pragma unroll
            for (int ks = 0; ks < 4; ++ks) {
                int rr = ks * 16 + ln;
                bh8 kv = *(const bh8*)&Klb[cur * 4096 + rr * 64 + ((dwin * 32 + hi * 8) ^ ((rr & 7) << 3))];
                sc[0][ks] = __builtin_amdgcn_mfma_f32_16x16x32_bf16(kv, qf[0][dwin], sc[0][ks], 0, 0, 0);
                sc[1][ks] = __builtin_amdgcn_mfma_f32_16x16x32_bf16(kv, qf[1][dwin], sc[1][ks], 0, 0, 0);
            }
        }
        __builtin_amdgcn_s_setprio(PLO);
        if (kt >= nt - 2) {  // tiles possibly crossing the causal diagonal
#pragma unroll
            for (int g = 0; g < 2; g++) {
                int qgq = qg0 + g * 16;
#pragma unroll
                for (int ks = 0; ks < 4; ++ks)
#pragma unroll
                    for (int rr = 0; rr < 4; ++rr) {
                        int kg = kt * 64 + ks * 16 + hi * 4 + rr;
                        sc[g][ks][rr] = (kg <= qgq) ? sc[g][ks][rr] : -1e30f;
                    }
            }
        }
        // fixed-base softmax: P = exp2(s) directly (s already includes 1/8*log2e from Q-proj)
        // l accumulated on VALU from f32 P (pre-truncation); pack truncates to bf16.
#pragma unroll
        for (int g = 0; g < 2; g++) {
#pragma unroll
            for (int ks = 0; ks < 4; ++ks) {
                float p0 = __builtin_amdgcn_exp2f(sc[g][ks][0]);
                float p1 = __builtin_amdgcn_exp2f(sc[g][ks][1]);
                float p2 = __builtin_amdgcn_exp2f(sc[g][ks][2]);
                float p3 = __builtin_amdgcn_exp2f(sc[g][ks][3]);
                ls[g] += (p0 + p1) + (p2 + p3);
                u32 u0 = __builtin_bit_cast(u32, p0);
                u32 u1 = __builtin_bit_cast(u32, p1);
                u32 u2 = __builtin_bit_cast(u32, p2);
                u32 u3 = __builtin_bit_cast(u32, p3);
                u32 a01 = (u0 >> 16) | (u1 & 0xffff0000u);   // truncating bf16 pack
                u32 a23 = (u2 >> 16) | (u3 & 0xffff0000u);
                int kloc = ks * 16 + hi * 4;
                *(u32x2*)&Pw[(g * 16 + ln) * 64 + (kloc ^ ((ln & 7) << 3))] = (u32x2){a01, a23};
            }
        }
        __builtin_amdgcn_s_setprio(PHI);
#pragma unroll
        for (int kw = 0; kw < 2; ++kw) {
            bh8 pf0 = *(const bh8*)&Pw[ln * 64 + ((kw * 32 + hi * 8) ^ ((ln & 7) << 3))];
            bh8 pf1 = *(const bh8*)&Pw[(16 + ln) * 64 + ((kw * 32 + hi * 8) ^ ((ln & 7) << 3))];
#pragma unroll
            for (int ds = 0; ds < 4; ++ds) {
                int d = ds * 16 + ln;
                bh8 vf = *(const bh8*)&Vlb[cur * 4096 + d * 64 + ((kw * 32 + hi * 8) ^ ((d & 7) << 3))];
                ctxa[0][ds] = __builtin_amdgcn_mfma_f32_16x16x32_bf16(vf, pf0, ctxa[0][ds], 0, 0, 0);
                ctxa[1][ds] = __builtin_amdgcn_mfma_f32_16x16x32_bf16(vf, pf1, ctxa[1][ds], 0, 0, 0);
            }
        }
        __builtin_amdgcn_s_setprio(PLO);
        __syncthreads();
        cur ^= 1;
    }
    // full row-sum l: combine the 4 hi-lane groups of each q column
#pragma unroll
    for (int g = 0; g < 2; g++) {
        ls[g] += __shfl_xor(ls[g], 16);
        ls[g] += __shfl_xor(ls[g], 32);
    }
    __builtin_amdgcn_s_setprio(0);
    // ---- intra-block combine: grp1 -> LDS, barrier, grp0 adds + normalizes + writes ----
    if (grp == 1) {
#pragma unroll
        for (int g = 0; g < 2; g++) {
            int qloc = g * 16 + ln;
#pragma unroll
            for (int ds = 0; ds < 4; ++ds) {
                int doff = (ds * 16 + hi * 4) ^ ((qloc & 7) << 3);  // bank-spread swizzle
                *(f32x4*)&Csh[(qsub * 32 + qloc) * 64 + doff] = ctxa[g][ds];
            }
            if (hi == 0) Ls[qsub * 32 + qloc] = ls[g];
        }
    }
    __syncthreads();
    if (grp == 0) {
#pragma unroll
        for (int g = 0; g < 2; g++) {
            int qloc = g * 16 + ln;
            float inv = 1.f / (ls[g] + Ls[qsub * 32 + qloc]);
            u16* cp = Ctx + ((size_t)(b * S_LEN + qg0 + g * 16)) * DMODEL + h * DHD;
#pragma unroll
            for (int ds = 0; ds < 4; ++ds) {
                int doff = (ds * 16 + hi * 4) ^ ((qloc & 7) << 3);
                f32x4 p = *(const f32x4*)&Csh[(qsub * 32 + qloc) * 64 + doff];
                ushort4 st;
                st.x = f2bf((ctxa[g][ds][0] + p[0]) * inv);
                st.y = f2bf((ctxa[g][ds][1] + p[1]) * inv);
                st.z = f2bf((ctxa[g][ds][2] + p[2]) * inv);
                st.w = f2bf((ctxa[g][ds][3] + p[3]) * inv);
                *(ushort4*)(cp + ds * 16 + hi * 4) = st;
            }
        }
    }
}

__global__ __launch_bounds__(512, 1) void attn_fwd(const u16* __restrict__ Qp, const u16* __restrict__ Kp,
                                                   const u16* __restrict__ VT, u16* __restrict__ Ctx) {
    __shared__ short Kl[2][2][4096];   // [grp][buf] 32KB
    __shared__ short Vl[2][2][4096];   // 32KB
    __shared__ short Pl[8][2048];      // per-wave 32x64 P, 32KB
    __shared__ float Ls[128];          // grp1 l partials (q-rows 0..127)
    int tid = threadIdx.x, w = tid >> 6;
    int grp = w >> 2;
    int bid = blockIdx.x;
    int rnd = bid >> 8, slot = bid & 255;
    int xcd = slot & 7, t = slot >> 3;       // t 0..31
    int bh = xcd * 4 + (t & 3);              // bh pinned to XCD both rounds (K/V L2)
    int qte = t >> 2;                        // 0..7
    int qt = rnd ? (15 - 2 * qte) : (2 * qte);  // rnd0: evens asc; rnd1: odds desc (greedy pairing)
    int b = bh >> 4, h = bh & 15;
    float* Csh = (float*)&Kl[0][0][0];       // 32KB combine buffer (reused after final barrier)
    if (qt >= 8)
        attn_core<2, 3>(Qp, Kp, VT, Ctx, &Kl[grp][0][0], &Vl[grp][0][0], &Pl[w][0], Csh, Ls, b, h, bh, qt, tid);
    else
        attn_core<0, 1>(Qp, Kp, VT, Ctx, &Kl[grp][0][0], &Vl[grp][0][0], &Pl[w][0], Csh, Ls, b, h, bh, qt, tid);
}

// ---------------- residual + LayerNorm ----------------
__global__ __launch_bounds__(256) void ln_res(const float* __restrict__ Xres, const float* __restrict__ Y,
                                              const float* __restrict__ gamma, const float* __restrict__ beta,
                                              float* __restrict__ out) {
    int row = blockIdx.x, tid = threadIdx.x;
    const float4* xr = (const float4*)(Xres + (size_t)row * DMODEL);
    const float4* yr = (const float4*)(Y + (size_t)row * DMODEL);
    float4 a = xr[tid], bq = yr[tid];
    float x0 = a.x + bq.x, x1 = a.y + bq.y, x2 = a.z + bq.z, x3 = a.w + bq.w;
    float s1 = x0 + x1 + x2 + x3;
    float s2 = x0 * x0 + x1 * x1 + x2 * x2 + x3 * x3;
#pragma unroll
    for (int off = 32; off > 0; off >>= 1) {
        s1 += __shfl_xor(s1, off);
        s2 += __shfl_xor(s2, off);
    }
    __shared__ float r1[4], r2[4];
    int wv = tid >> 6;
    if ((tid & 63) == 0) { r1[wv] = s1; r2[wv] = s2; }
    __syncthreads();
    s1 = r1[0] + r1[1] + r1[2] + r1[3];
    s2 = r2[0] + r2[1] + r2[2] + r2[3];
    float mu = s1 * (1.0f / 1024.0f);
    float var = s2 * (1.0f / 1024.0f) - mu * mu;
    float rstd = rsqrtf(var + 1e-5f);
    const float4* g4 = (const float4*)gamma;
    const float4* b4 = (const float4*)beta;
    float4 g = g4[tid], bb = b4[tid];
    float4 res;
    res.x = (x0 - mu) * rstd * g.x + bb.x;
    res.y = (x1 - mu) * rstd * g.y + bb.y;
    res.z = (x2 - mu) * rstd * g.z + bb.z;
    res.w = (x3 - mu) * rstd * g.w + bb.w;
    *((float4*)(out + (size_t)row * DMODEL) + tid) = res;
}

extern "C" void kernel_launch(void* const* d_in, const int* in_sizes, int n_in,
                              void* d_out, int out_size, void* d_ws, size_t ws_size,
                              hipStream_t stream) {
    const float* Qs = (const float*)d_in[0];
    const float* Ks = (const float*)d_in[1];
    const float* Vs = (const float*)d_in[2];
    const float* WQ = (const float*)d_in[5];
    const float* bQ = (const float*)d_in[6];
    const float* WK = (const float*)d_in[7];
    const float* bK = (const float*)d_in[8];
    const float* WV = (const float*)d_in[9];
    const float* bV = (const float*)d_in[10];
    const float* WO = (const float*)d_in[11];
    const float* bO = (const float*)d_in[12];
    const float* gamma = (const float*)d_in[13];
    const float* beta = (const float*)d_in[14];

    const size_t MB = 1u << 20;
    char* w8 = (char*)d_ws;
    u16* Qb  = (u16*)(w8 + 0 * MB);   // bf16 sources (8MB each)
    u16* Kb  = (u16*)(w8 + 8 * MB);
    u16* Vb  = (u16*)(w8 + 16 * MB);
    u16* WQb = (u16*)(w8 + 24 * MB);
    u16* WKb = (u16*)(w8 + 26 * MB);
    u16* WVb = (u16*)(w8 + 28 * MB);
    u16* WOb = (u16*)(w8 + 30 * MB);
    u16* Qp  = (u16*)(w8 + 32 * MB);
    u16* Kp  = (u16*)(w8 + 40 * MB);
    u16* VTb = (u16*)(w8 + 56 * MB);
    u16* Ctx = (u16*)(w8 + 64 * MB);
    float* Y2 = (float*)(w8 + 72 * MB);

    cvt_all<<<8192, 256, 0, stream>>>(WQ, WK, WV, WO, Qs, Ks, Vs, WQb, WKb, WVb, WOb, Qb, Kb, Vb);
    gemm_qkv<<<768, 256, 0, stream>>>(Qb, Kb, Vb, WQb, WKb, WVb, bQ, bK, bV, Qp, Kp, VTb);
    attn_fwd<<<512, 512, 0, stream>>>(Qp, Kp, VTb, Ctx);
    gemm_o<<<512, 256, 0, stream>>>(Ctx, WOb, bO, Y2);
    ln_res<<<4096, 256, 0, stream>>>(Qs, Y2, gamma, beta, (float*)d_out);
}

// Round 11
// 112.338 us; speedup vs baseline: 1.3681x; 1.0116x over previous
//
#include <hip/hip_runtime.h>

#define S_LEN 2048
#define DMODEL 1024
#define NH 16
#define DHD 64

typedef __attribute__((ext_vector_type(8))) short bh8;
typedef __attribute__((ext_vector_type(4))) float f32x4;
typedef __attribute__((ext_vector_type(2))) unsigned int u32x2;
typedef __attribute__((ext_vector_type(4))) unsigned int u32x4;
typedef unsigned short u16;
typedef unsigned int u32;

static __device__ __forceinline__ u16 f2bf(float f) {
    unsigned u = __builtin_bit_cast(unsigned, f);
    u += 0x7fffu + ((u >> 16) & 1u);
    return (u16)(u >> 16);
}

typedef const __attribute__((address_space(1))) void* gptr_t;
typedef __attribute__((address_space(3))) void* lptr_t;

static __device__ __forceinline__ void gll16(const void* g, void* l) {
    __builtin_amdgcn_global_load_lds((gptr_t)g, (lptr_t)l, 16, 0, 0);
}

// ---------------- convert fp32 -> bf16: weights (4x1M) + sources (3x4M) --------------
__global__ __launch_bounds__(256) void cvt_all(const float* __restrict__ WQ, const float* __restrict__ WK,
                                               const float* __restrict__ WV, const float* __restrict__ WO,
                                               const float* __restrict__ S0, const float* __restrict__ S1,
                                               const float* __restrict__ S2,
                                               u16* __restrict__ wq, u16* __restrict__ wk,
                                               u16* __restrict__ wv, u16* __restrict__ wo,
                                               u16* __restrict__ q0, u16* __restrict__ k0,
                                               u16* __restrict__ v0) {
    int bid = blockIdx.x;
    const float* s;
    u16* o;
    size_t base;
    if (bid < 2048) {
        int wi = bid >> 9;
        s = wi == 0 ? WQ : (wi == 1 ? WK : (wi == 2 ? WV : WO));
        o = wi == 0 ? wq : (wi == 1 ? wk : (wi == 2 ? wv : wo));
        base = (size_t)(bid & 511) * 2048;
    } else {
        int r = bid - 2048;
        int si = r >> 11;
        s = si == 0 ? S0 : (si == 1 ? S1 : S2);
        o = si == 0 ? q0 : (si == 1 ? k0 : v0);
        base = (size_t)(r & 2047) * 2048;
    }
    size_t i = base + (size_t)threadIdx.x * 8;
    float4 a = *(const float4*)(s + i);
    float4 b = *(const float4*)(s + i + 4);
    u32 p0 = (u32)f2bf(a.x) | ((u32)f2bf(a.y) << 16);
    u32 p1 = (u32)f2bf(a.z) | ((u32)f2bf(a.w) << 16);
    u32 p2 = (u32)f2bf(b.x) | ((u32)f2bf(b.y) << 16);
    u32 p3 = (u32)f2bf(b.z) | ((u32)f2bf(b.w) << 16);
    *(u32x4*)(o + i) = (u32x4){p0, p1, p2, p3};
}

// ---------------- GEMM body: C[M,N] = A[M,K]*B[N,K]^T + bias, 2-phase dbuf ----------------
template <int BM, int OBF, int AF32>
static __device__ __forceinline__ void gemm_body(const void* __restrict__ Ap, const u16* __restrict__ Bm,
                                                 const float* __restrict__ bias, void* __restrict__ Cv,
                                                 int N, int K, int bi, int bj, short* Al, short* Bl,
                                                 float oscale) {
    constexpr int MI = BM / 32;
    constexpr int NC = BM / 64;
    int tid = threadIdx.x, lane = tid & 63, w = tid >> 6;
    int ln = lane & 15, hi = lane >> 4;
    int wm = w >> 1, wn = w & 1;
    f32x4 acc[MI][4];
#pragma unroll
    for (int i = 0; i < MI; i++)
#pragma unroll
        for (int j = 0; j < 4; j++) acc[i][j] = (f32x4){0.f, 0.f, 0.f, 0.f};
    int nk = K >> 5;

    float4 fa[NC][2];  // in-flight f32 A (AF32 path)
    auto loadA = [&](int kt) {
#pragma unroll
        for (int c = 0; c < NC; ++c) {
            int o = c * 4096 + tid * 16;
            int row = o >> 6, e0 = (o & 63) >> 1;
            const float* src = (const float*)Ap + (size_t)(bi * BM + row) * K + kt * 32 + e0;
            fa[c][0] = *(const float4*)src;
            fa[c][1] = *(const float4*)(src + 4);
        }
    };
    auto writeA = [&](int buf) {
#pragma unroll
        for (int c = 0; c < NC; ++c) {
            int o = c * 4096 + tid * 16;
            u32 w0 = (u32)f2bf(fa[c][0].x) | ((u32)f2bf(fa[c][0].y) << 16);
            u32 w1 = (u32)f2bf(fa[c][0].z) | ((u32)f2bf(fa[c][0].w) << 16);
            u32 w2 = (u32)f2bf(fa[c][1].x) | ((u32)f2bf(fa[c][1].y) << 16);
            u32 w3 = (u32)f2bf(fa[c][1].z) | ((u32)f2bf(fa[c][1].w) << 16);
            *(u32x4*)((char*)(Al + buf * (BM * 32)) + o) = (u32x4){w0, w1, w2, w3};
        }
    };
    auto stageA_lds = [&](int buf, int kt) {
#pragma unroll
        for (int c = 0; c < NC; ++c) {
            int o = c * 4096 + tid * 16;
            int row = o >> 6, col = (o & 63) >> 1;
            gll16((const u16*)Ap + (size_t)(bi * BM + row) * K + kt * 32 + col,
                  (char*)(Al + buf * (BM * 32)) + o);
        }
    };
    auto stageB = [&](int buf, int kt) {
#pragma unroll
        for (int c = 0; c < 2; ++c) {
            int o = c * 4096 + tid * 16;
            int row = o >> 6, col = (o & 63) >> 1;
            gll16(Bm + (size_t)(bj * 128 + row) * K + kt * 32 + col, (char*)(Bl + buf * 4096) + o);
        }
    };

    if constexpr (AF32) { loadA(0); writeA(0); } else { stageA_lds(0, 0); }
    stageB(0, 0);
    __syncthreads();
    int cur = 0;
    for (int kt = 0; kt < nk; ++kt) {
        bool pre = (kt + 1 < nk);
        if (pre) {
            if constexpr (AF32) loadA(kt + 1); else stageA_lds(cur ^ 1, kt + 1);
            stageB(cur ^ 1, kt + 1);
        }
        bh8 av[MI], bv[4];
#pragma unroll
        for (int i = 0; i < MI; i++) av[i] = *(const bh8*)&Al[cur * (BM * 32) + (wm * (BM / 2) + i * 16 + ln) * 32 + hi * 8];
#pragma unroll
        for (int j = 0; j < 4; j++) bv[j] = *(const bh8*)&Bl[cur * 4096 + (wn * 64 + j * 16 + ln) * 32 + hi * 8];
#pragma unroll
        for (int i = 0; i < MI; i++)
#pragma unroll
            for (int j = 0; j < 4; j++)
                acc[i][j] = __builtin_amdgcn_mfma_f32_16x16x32_bf16(av[i], bv[j], acc[i][j], 0, 0, 0);
        if constexpr (AF32) { if (pre) writeA(cur ^ 1); }
        __syncthreads();
        cur ^= 1;
    }
    if constexpr (OBF == 2) {
        // V projection: write C^T into VT[b,h,d,s] via LDS transpose (reuses Al+Bl = 32KB)
#pragma unroll
        for (int j = 0; j < 4; j++) {
            int col = wn * 64 + j * 16 + ln;  // local d_model col 0..127
            float bvs = bias[bj * 128 + col];
#pragma unroll
            for (int i = 0; i < MI; i++) {
                int row0 = wm * (BM / 2) + i * 16 + hi * 4;  // local s row
                u32 p01 = (u32)f2bf(acc[i][j][0] + bvs) | ((u32)f2bf(acc[i][j][1] + bvs) << 16);
                u32 p23 = (u32)f2bf(acc[i][j][2] + bvs) | ((u32)f2bf(acc[i][j][3] + bvs) << 16);
                int idx = col * 128 + (row0 ^ ((col & 7) << 3));
                *(u32x2*)&Al[idx] = (u32x2){p01, p23};
            }
        }
        __syncthreads();
        int b = bi >> 4;
        int sbase = (bi & 15) * 128;
#pragma unroll
        for (int it = 0; it < 8; ++it) {
            int idx = it * 256 + tid;
            int dcol = idx >> 4;           // 0..127
            int sl = (idx & 15) * 8;       // 0..120
            bh8 v = *(const bh8*)&Al[dcol * 128 + (sl ^ ((dcol & 7) << 3))];
            int h = bj * 2 + (dcol >> 6), d = dcol & 63;
            *(bh8*)((u16*)Cv + ((size_t)((b * 16 + h) * 64 + d)) * 2048 + sbase + sl) = v;
        }
        return;
    }
#pragma unroll
    for (int j = 0; j < 4; j++) {
        int col = bj * 128 + wn * 64 + j * 16 + ln;
        float bvs = bias[col];
#pragma unroll
        for (int i = 0; i < MI; i++) {
            int row0 = bi * BM + wm * (BM / 2) + i * 16 + hi * 4;
#pragma unroll
            for (int rr = 0; rr < 4; rr++) {
                if (OBF) {
                    float v = (acc[i][j][rr] + bvs) * oscale;  // Q-proj folds softmax scale here
                    ((u16*)Cv)[(size_t)(row0 + rr) * N + col] = f2bf(v);
                } else {
                    ((float*)Cv)[(size_t)(row0 + rr) * N + col] = acc[i][j][rr] + bvs;
                }
            }
        }
    }
}

// fused QKV projections, A pre-converted to bf16: grid 768 (XCD-swizzled); z==2 (V) writes VT
__global__ __launch_bounds__(256, 3) void gemm_qkv(const u16* __restrict__ A0, const u16* __restrict__ A1,
                                                   const u16* __restrict__ A2, const u16* __restrict__ B0,
                                                   const u16* __restrict__ B1, const u16* __restrict__ B2,
                                                   const float* __restrict__ c0, const float* __restrict__ c1,
                                                   const float* __restrict__ c2, u16* __restrict__ C0,
                                                   u16* __restrict__ C1, u16* __restrict__ VT) {
    __shared__ short SH[16384];  // 32KB: Al(16KB) + Bl(16KB); reused whole for V transpose
    short* Al = SH;
    short* Bl = SH + 8192;
    int bid = blockIdx.x;
    int swz = (bid & 7) * 96 + (bid >> 3);
    int z = swz >> 8, t = swz & 255;
    if (z == 2) {
        gemm_body<128, 2, 0>(A2, B2, c2, VT, 1024, 1024, t >> 3, t & 7, Al, Bl, 1.0f);
    } else if (z == 0) {
        gemm_body<128, 1, 0>(A0, B0, c0, C0, 1024, 1024, t >> 3, t & 7, Al, Bl, 0.18033688f);
    } else {
        gemm_body<128, 1, 0>(A1, B1, c1, C1, 1024, 1024, t >> 3, t & 7, Al, Bl, 1.0f);
    }
}

// ---------------- output projection: 64x128 tile, 8 waves (R10: 2x occupancy) ------------
// R10: gemm_o was the lowest-occupancy kernel (4 waves/block = 8 waves/CU, ~450 TF vs the
// 920 TF structure ceiling). Same tile/grid/LDS/barriers; 512 threads: wave (wm=w>>2,
// wn=w&3) owns a 32x32 sub-tile (acc[2][2]). 16 waves/CU doubles the latency-hiding pool.
__global__ __launch_bounds__(512, 4) void gemm_o(const u16* __restrict__ A, const u16* __restrict__ Bm,
                                                 const float* __restrict__ bias, float* __restrict__ C) {
    __shared__ short Al[2 * 64 * 32];    // 8KB
    __shared__ short Bl[2 * 128 * 32];   // 16KB
    int tid = threadIdx.x, lane = tid & 63, w = tid >> 6;
    int ln = lane & 15, hi = lane >> 4;
    int wm = w >> 2, wn = w & 3;
    int bid = blockIdx.x;
    int swz = (bid & 7) * 64 + (bid >> 3);
    int bi = swz >> 3, bj = swz & 7;
    f32x4 acc[2][2];
#pragma unroll
    for (int i = 0; i < 2; i++)
#pragma unroll
        for (int j = 0; j < 2; j++) acc[i][j] = (f32x4){0.f, 0.f, 0.f, 0.f};

    auto stageA = [&](int buf, int kt) {
        if (tid < 256) {                     // waves 0-3 (wave-uniform predicate)
            int o = tid * 16;                // 256 x 16B = 4KB = 64x32 bf16
            int row = o >> 6, col = (o & 63) >> 1;
            gll16(A + (size_t)(bi * 64 + row) * 1024 + kt * 32 + col, (char*)(Al + buf * 2048) + o);
        }
    };
    auto stageB = [&](int buf, int kt) {
        int o = tid * 16;                    // 512 x 16B = 8KB = 128x32 bf16
        int row = o >> 6, col = (o & 63) >> 1;
        gll16(Bm + (size_t)(bj * 128 + row) * 1024 + kt * 32 + col, (char*)(Bl + buf * 4096) + o);
    };

    stageA(0, 0);
    stageB(0, 0);
    __syncthreads();
    int cur = 0;
    for (int kt = 0; kt < 32; ++kt) {
        if (kt + 1 < 32) {
            stageA(cur ^ 1, kt + 1);
            stageB(cur ^ 1, kt + 1);
        }
        bh8 av[2], bv[2];
#pragma unroll
        for (int i = 0; i < 2; i++) av[i] = *(const bh8*)&Al[cur * 2048 + (wm * 32 + i * 16 + ln) * 32 + hi * 8];
#pragma unroll
        for (int j = 0; j < 2; j++) bv[j] = *(const bh8*)&Bl[cur * 4096 + (wn * 32 + j * 16 + ln) * 32 + hi * 8];
#pragma unroll
        for (int i = 0; i < 2; i++)
#pragma unroll
            for (int j = 0; j < 2; j++)
                acc[i][j] = __builtin_amdgcn_mfma_f32_16x16x32_bf16(av[i], bv[j], acc[i][j], 0, 0, 0);
        __syncthreads();
        cur ^= 1;
    }
#pragma unroll
    for (int j = 0; j < 2; j++) {
        int col = bj * 128 + wn * 32 + j * 16 + ln;
        float bvs = bias[col];
#pragma unroll
        for (int i = 0; i < 2; i++) {
            int row0 = bi * 64 + wm * 32 + i * 16 + hi * 4;
#pragma unroll
            for (int rr = 0; rr < 4; rr++)
                C[(size_t)(row0 + rr) * 1024 + col] = acc[i][j][rr] + bvs;
        }
    }
}

// ------- flash attention (causal): INTRA-BLOCK SPLIT-KV, LDS reduction (R6 = best) -------
// Proven 112.9us configuration, reverted byte-exact: waves 0-3 take kv tiles [0,qt],
// waves 4-7 take [qt+1,2qt+1] (both exactly qt+1 tiles -> uniform loop/barriers), each
// wave 32 q-rows. Fixed-base softmax => partials additive; epilogue: grp1 writes ctx/l to
// LDS, barrier, grp0 combines+normalizes+writes. Critical chain 32 -> 16 tiles. 1 block/CU.
template <int PLO, int PHI>
static __device__ __forceinline__ void attn_core(const u16* __restrict__ Qp, const u16* __restrict__ Kp,
                                                 const u16* __restrict__ VT, u16* __restrict__ Ctx,
                                                 short* Klb, short* Vlb, short* Pw, float* Csh, float* Ls,
                                                 int b, int h, int bh, int qt, int tid) {
    int lane = tid & 63, w = tid >> 6;       // w 0..7
    int grp = w >> 2;                        // kv chunk group
    int qsub = w & 3;                        // q-slot within group (32 rows each)
    int tgl = tid & 255;                     // thread id within group
    int ln = lane & 15, hi = lane >> 4;
    __builtin_amdgcn_s_setprio(PLO);
    bh8 ones;
#pragma unroll
    for (int e = 0; e < 8; e++) ones[e] = (short)0x3F80;  // bf16 1.0

    // per-group staging: Klb/Vlb point at this group's dbuf area (2 x 8KB each)
    auto stage_kv = [&](int buf, int kt) {
#pragma unroll
        for (int c = 0; c < 2; ++c) {
            int o = c * 4096 + tgl * 16;     // 256 threads x 2 x 16B = 8KB per matrix
            int rr = o >> 7;
            int slot = (o >> 4) & 7;
            gll16(Kp + ((size_t)(b * S_LEN + kt * 64 + rr)) * DMODEL + h * DHD + ((slot ^ (rr & 7)) << 3),
                  (char*)(Klb + buf * 4096) + o);
            gll16(VT + ((size_t)(bh * DHD + rr)) * S_LEN + kt * 64 + ((slot ^ (rr & 7)) << 3),
                  (char*)(Vlb + buf * 4096) + o);
        }
    };

    int nh = qt + 1;                         // tiles per group
    int nt = 2 * qt + 2;                     // total causal kv tiles
    int kbase = grp * nh;
    int qg0 = (qt << 7) + qsub * 32 + ln;    // q-group 0 row; group 1 = qg0 + 16
    const bh8* qr0 = (const bh8*)(Qp + ((size_t)(b * S_LEN + qg0)) * DMODEL + h * DHD);
    const bh8* qr1 = (const bh8*)(Qp + ((size_t)(b * S_LEN + qg0 + 16)) * DMODEL + h * DHD);
    bh8 qf[2][2];
    qf[0][0] = qr0[hi]; qf[0][1] = qr0[4 + hi];
    qf[1][0] = qr1[hi]; qf[1][1] = qr1[4 + hi];
    f32x4 ctxa[2][4];
    f32x4 lacc[2];
#pragma unroll
    for (int g = 0; g < 2; g++) {
        lacc[g] = (f32x4){0.f, 0.f, 0.f, 0.f};
#pragma unroll
        for (int i = 0; i < 4; i++) ctxa[g][i] = (f32x4){0.f, 0.f, 0.f, 0.f};
    }
    stage_kv(0, kbase);
    __syncthreads();
    int cur = 0;
    for (int i = 0; i < nh; ++i) {
        int kt = kbase + i;
        if (i + 1 < nh) stage_kv(cur ^ 1, kt + 1);
        f32x4 sc[2][4];
#pragma unroll
        for (int g = 0; g < 2; g++)
#pragma unroll
            for (int ks = 0; ks < 4; ++ks) sc[g][ks] = (f32x4){0.f, 0.f, 0.f, 0.f};
        __builtin_amdgcn_s_setprio(PHI);
#pragma unroll
        for (int dwin = 0; dwin < 2; ++dwin) {
#pragma unroll
            for (int ks = 0; ks < 4; ++ks) {
                int rr = ks * 16 + ln;
                bh8 kv = *(const bh8*)&Klb[cur * 4096 + rr * 64 + ((dwin * 32 + hi * 8) ^ ((rr & 7) << 3))];
                sc[0][ks] = __builtin_amdgcn_mfma_f32_16x16x32_bf16(kv, qf[0][dwin], sc[0][ks], 0, 0, 0);
                sc[1][ks] = __builtin_amdgcn_mfma_f32_16x16x32_bf16(kv, qf[1][dwin], sc[1][ks], 0, 0, 0);
            }
        }
        __builtin_amdgcn_s_setprio(PLO);
        if (kt >= nt - 2) {  // tiles possibly crossing the causal diagonal
#pragma unroll
            for (int g = 0; g < 2; g++) {
                int qgq = qg0 + g * 16;
#pragma unroll
                for (int ks = 0; ks < 4; ++ks)
#pragma unroll
                    for (int rr = 0; rr < 4; ++rr) {
                        int kg = kt * 64 + ks * 16 + hi * 4 + rr;
                        sc[g][ks][rr] = (kg <= qgq) ? sc[g][ks][rr] : -1e30f;
                    }
            }
        }
        // fixed-base softmax: P = exp2(s) directly (s already includes 1/8*log2e from Q-proj)
#pragma unroll
        for (int g = 0; g < 2; g++) {
#pragma unroll
            for (int ks = 0; ks < 4; ++ks) {
                u32 u0 = __builtin_bit_cast(u32, __builtin_amdgcn_exp2f(sc[g][ks][0]));
                u32 u1 = __builtin_bit_cast(u32, __builtin_amdgcn_exp2f(sc[g][ks][1]));
                u32 u2 = __builtin_bit_cast(u32, __builtin_amdgcn_exp2f(sc[g][ks][2]));
                u32 u3 = __builtin_bit_cast(u32, __builtin_amdgcn_exp2f(sc[g][ks][3]));
                // truncating bf16 pack (l computed from the same truncated P)
                u32 a01 = (u0 >> 16) | (u1 & 0xffff0000u);
                u32 a23 = (u2 >> 16) | (u3 & 0xffff0000u);
                int kloc = ks * 16 + hi * 4;
                *(u32x2*)&Pw[(g * 16 + ln) * 64 + (kloc ^ ((ln & 7) << 3))] = (u32x2){a01, a23};
            }
        }
        __builtin_amdgcn_s_setprio(PHI);
#pragma unroll
        for (int kw = 0; kw < 2; ++kw) {
            bh8 pf0 = *(const bh8*)&Pw[ln * 64 + ((kw * 32 + hi * 8) ^ ((ln & 7) << 3))];
            bh8 pf1 = *(const bh8*)&Pw[(16 + ln) * 64 + ((kw * 32 + hi * 8) ^ ((ln & 7) << 3))];
            lacc[0] = __builtin_amdgcn_mfma_f32_16x16x32_bf16(ones, pf0, lacc[0], 0, 0, 0);
            lacc[1] = __builtin_amdgcn_mfma_f32_16x16x32_bf16(ones, pf1, lacc[1], 0, 0, 0);
#pragma unroll
            for (int ds = 0; ds < 4; ++ds) {
                int d = ds * 16 + ln;
                bh8 vf = *(const bh8*)&Vlb[cur * 4096 + d * 64 + ((kw * 32 + hi * 8) ^ ((d & 7) << 3))];
                ctxa[0][ds] = __builtin_amdgcn_mfma_f32_16x16x32_bf16(vf, pf0, ctxa[0][ds], 0, 0, 0);
                ctxa[1][ds] = __builtin_amdgcn_mfma_f32_16x16x32_bf16(vf, pf1, ctxa[1][ds], 0, 0, 0);
            }
        }
        __builtin_amdgcn_s_setprio(PLO);
        __syncthreads();
        cur ^= 1;
    }
    __builtin_amdgcn_s_setprio(0);
    // ---- intra-block combine: grp1 -> LDS, barrier, grp0 adds + normalizes + writes ----
    if (grp == 1) {
#pragma unroll
        for (int g = 0; g < 2; g++) {
            int qloc = g * 16 + ln;
#pragma unroll
            for (int ds = 0; ds < 4; ++ds) {
                int doff = (ds * 16 + hi * 4) ^ ((qloc & 7) << 3);  // bank-spread swizzle
                *(f32x4*)&Csh[(qsub * 32 + qloc) * 64 + doff] = ctxa[g][ds];
            }
            if (hi == 0) Ls[qsub * 32 + qloc] = lacc[g][0];
        }
    }
    __syncthreads();
    if (grp == 0) {
#pragma unroll
        for (int g = 0; g < 2; g++) {
            int qloc = g * 16 + ln;
            float inv = 1.f / (lacc[g][0] + Ls[qsub * 32 + qloc]);
            u16* cp = Ctx + ((size_t)(b * S_LEN + qg0 + g * 16)) * DMODEL + h * DHD;
#pragma unroll
            for (int ds = 0; ds < 4; ++ds) {
                int doff = (ds * 16 + hi * 4) ^ ((qloc & 7) << 3);
                f32x4 p = *(const f32x4*)&Csh[(qsub * 32 + qloc) * 64 + doff];
                ushort4 st;
                st.x = f2bf((ctxa[g][ds][0] + p[0]) * inv);
                st.y = f2bf((ctxa[g][ds][1] + p[1]) * inv);
                st.z = f2bf((ctxa[g][ds][2] + p[2]) * inv);
                st.w = f2bf((ctxa[g][ds][3] + p[3]) * inv);
                *(ushort4*)(cp + ds * 16 + hi * 4) = st;
            }
        }
    }
}

__global__ __launch_bounds__(512, 1) void attn_fwd(const u16* __restrict__ Qp, const u16* __restrict__ Kp,
                                                   const u16* __restrict__ VT, u16* __restrict__ Ctx) {
    __shared__ short Kl[2][2][4096];   // [grp][buf] 32KB
    __shared__ short Vl[2][2][4096];   // 32KB
    __shared__ short Pl[8][2048];      // per-wave 32x64 P, 32KB
    __shared__ float Ls[128];          // grp1 l partials (q-rows 0..127)
    int tid = threadIdx.x, w = tid >> 6;
    int grp = w >> 2;
    int bid = blockIdx.x;
    int rnd = bid >> 8, slot = bid & 255;
    int xcd = slot & 7, t = slot >> 3;       // t 0..31
    int bh = xcd * 4 + (t & 3);              // bh pinned to XCD both rounds (K/V L2)
    int qte = t >> 2;                        // 0..7
    int qt = rnd ? (15 - 2 * qte) : (2 * qte);  // rnd0: evens asc; rnd1: odds desc (greedy pairing)
    int b = bh >> 4, h = bh & 15;
    float* Csh = (float*)&Kl[0][0][0];       // 32KB combine buffer (reused after final barrier)
    if (qt >= 8)
        attn_core<2, 3>(Qp, Kp, VT, Ctx, &Kl[grp][0][0], &Vl[grp][0][0], &Pl[w][0], Csh, Ls, b, h, bh, qt, tid);
    else
        attn_core<0, 1>(Qp, Kp, VT, Ctx, &Kl[grp][0][0], &Vl[grp][0][0], &Pl[w][0], Csh, Ls, b, h, bh, qt, tid);
}

// ---------------- residual + LayerNorm ----------------
__global__ __launch_bounds__(256) void ln_res(const float* __restrict__ Xres, const float* __restrict__ Y,
                                              const float* __restrict__ gamma, const float* __restrict__ beta,
                                              float* __restrict__ out) {
    int row = blockIdx.x, tid = threadIdx.x;
    const float4* xr = (const float4*)(Xres + (size_t)row * DMODEL);
    const float4* yr = (const float4*)(Y + (size_t)row * DMODEL);
    float4 a = xr[tid], bq = yr[tid];
    float x0 = a.x + bq.x, x1 = a.y + bq.y, x2 = a.z + bq.z, x3 = a.w + bq.w;
    float s1 = x0 + x1 + x2 + x3;
    float s2 = x0 * x0 + x1 * x1 + x2 * x2 + x3 * x3;
#pragma unroll
    for (int off = 32; off > 0; off >>= 1) {
        s1 += __shfl_xor(s1, off);
        s2 += __shfl_xor(s2, off);
    }
    __shared__ float r1[4], r2[4];
    int wv = tid >> 6;
    if ((tid & 63) == 0) { r1[wv] = s1; r2[wv] = s2; }
    __syncthreads();
    s1 = r1[0] + r1[1] + r1[2] + r1[3];
    s2 = r2[0] + r2[1] + r2[2] + r2[3];
    float mu = s1 * (1.0f / 1024.0f);
    float var = s2 * (1.0f / 1024.0f) - mu * mu;
    float rstd = rsqrtf(var + 1e-5f);
    const float4* g4 = (const float4*)gamma;
    const float4* b4 = (const float4*)beta;
    float4 g = g4[tid], bb = b4[tid];
    float4 res;
    res.x = (x0 - mu) * rstd * g.x + bb.x;
    res.y = (x1 - mu) * rstd * g.y + bb.y;
    res.z = (x2 - mu) * rstd * g.z + bb.z;
    res.w = (x3 - mu) * rstd * g.w + bb.w;
    *((float4*)(out + (size_t)row * DMODEL) + tid) = res;
}

extern "C" void kernel_launch(void* const* d_in, const int* in_sizes, int n_in,
                              void* d_out, int out_size, void* d_ws, size_t ws_size,
                              hipStream_t stream) {
    const float* Qs = (const float*)d_in[0];
    const float* Ks = (const float*)d_in[1];
    const float* Vs = (const float*)d_in[2];
    const float* WQ = (const float*)d_in[5];
    const float* bQ = (const float*)d_in[6];
    const float* WK = (const float*)d_in[7];
    const float* bK = (const float*)d_in[8];
    const float* WV = (const float*)d_in[9];
    const float* bV = (const float*)d_in[10];
    const float* WO = (const float*)d_in[11];
    const float* bO = (const float*)d_in[12];
    const float* gamma = (const float*)d_in[13];
    const float* beta = (const float*)d_in[14];

    const size_t MB = 1u << 20;
    char* w8 = (char*)d_ws;
    u16* Qb  = (u16*)(w8 + 0 * MB);   // bf16 sources (8MB each)
    u16* Kb  = (u16*)(w8 + 8 * MB);
    u16* Vb  = (u16*)(w8 + 16 * MB);
    u16* WQb = (u16*)(w8 + 24 * MB);
    u16* WKb = (u16*)(w8 + 26 * MB);
    u16* WVb = (u16*)(w8 + 28 * MB);
    u16* WOb = (u16*)(w8 + 30 * MB);
    u16* Qp  = (u16*)(w8 + 32 * MB);
    u16* Kp  = (u16*)(w8 + 40 * MB);
    u16* VTb = (u16*)(w8 + 56 * MB);
    u16* Ctx = (u16*)(w8 + 64 * MB);
    float* Y2 = (float*)(w8 + 72 * MB);

    cvt_all<<<8192, 256, 0, stream>>>(WQ, WK, WV, WO, Qs, Ks, Vs, WQb, WKb, WVb, WOb, Qb, Kb, Vb);
    gemm_qkv<<<768, 256, 0, stream>>>(Qb, Kb, Vb, WQb, WKb, WVb, bQ, bK, bV, Qp, Kp, VTb);
    attn_fwd<<<512, 512, 0, stream>>>(Qp, Kp, VTb, Ctx);
    gemm_o<<<512, 512, 0, stream>>>(Ctx, WOb, bO, Y2);
    ln_res<<<4096, 256, 0, stream>>>(Qs, Y2, gamma, beta, (float*)d_out);
}

// Round 12
// 109.810 us; speedup vs baseline: 1.3996x; 1.0230x over previous
//
#include <hip/hip_runtime.h>

#define S_LEN 2048
#define DMODEL 1024
#define NH 16
#define DHD 64

typedef __attribute__((ext_vector_type(8))) short bh8;
typedef __attribute__((ext_vector_type(4))) float f32x4;
typedef __attribute__((ext_vector_type(2))) unsigned int u32x2;
typedef __attribute__((ext_vector_type(4))) unsigned int u32x4;
typedef unsigned short u16;
typedef unsigned int u32;

static __device__ __forceinline__ u16 f2bf(float f) {
    unsigned u = __builtin_bit_cast(unsigned, f);
    u += 0x7fffu + ((u >> 16) & 1u);
    return (u16)(u >> 16);
}

typedef const __attribute__((address_space(1))) void* gptr_t;
typedef __attribute__((address_space(3))) void* lptr_t;

static __device__ __forceinline__ void gll16(const void* g, void* l) {
    __builtin_amdgcn_global_load_lds((gptr_t)g, (lptr_t)l, 16, 0, 0);
}

// ---------------- convert fp32 -> bf16: weights (4x1M) + sources (3x4M) --------------
__global__ __launch_bounds__(256) void cvt_all(const float* __restrict__ WQ, const float* __restrict__ WK,
                                               const float* __restrict__ WV, const float* __restrict__ WO,
                                               const float* __restrict__ S0, const float* __restrict__ S1,
                                               const float* __restrict__ S2,
                                               u16* __restrict__ wq, u16* __restrict__ wk,
                                               u16* __restrict__ wv, u16* __restrict__ wo,
                                               u16* __restrict__ q0, u16* __restrict__ k0,
                                               u16* __restrict__ v0) {
    int bid = blockIdx.x;
    const float* s;
    u16* o;
    size_t base;
    if (bid < 2048) {
        int wi = bid >> 9;
        s = wi == 0 ? WQ : (wi == 1 ? WK : (wi == 2 ? WV : WO));
        o = wi == 0 ? wq : (wi == 1 ? wk : (wi == 2 ? wv : wo));
        base = (size_t)(bid & 511) * 2048;
    } else {
        int r = bid - 2048;
        int si = r >> 11;
        s = si == 0 ? S0 : (si == 1 ? S1 : S2);
        o = si == 0 ? q0 : (si == 1 ? k0 : v0);
        base = (size_t)(r & 2047) * 2048;
    }
    size_t i = base + (size_t)threadIdx.x * 8;
    float4 a = *(const float4*)(s + i);
    float4 b = *(const float4*)(s + i + 4);
    u32 p0 = (u32)f2bf(a.x) | ((u32)f2bf(a.y) << 16);
    u32 p1 = (u32)f2bf(a.z) | ((u32)f2bf(a.w) << 16);
    u32 p2 = (u32)f2bf(b.x) | ((u32)f2bf(b.y) << 16);
    u32 p3 = (u32)f2bf(b.z) | ((u32)f2bf(b.w) << 16);
    *(u32x4*)(o + i) = (u32x4){p0, p1, p2, p3};
}

// ---------------- GEMM body: C[M,N] = A[M,K]*B[N,K]^T + bias, 2-phase dbuf ----------------
template <int BM, int OBF, int AF32>
static __device__ __forceinline__ void gemm_body(const void* __restrict__ Ap, const u16* __restrict__ Bm,
                                                 const float* __restrict__ bias, void* __restrict__ Cv,
                                                 int N, int K, int bi, int bj, short* Al, short* Bl,
                                                 float oscale) {
    constexpr int MI = BM / 32;
    constexpr int NC = BM / 64;
    int tid = threadIdx.x, lane = tid & 63, w = tid >> 6;
    int ln = lane & 15, hi = lane >> 4;
    int wm = w >> 1, wn = w & 1;
    f32x4 acc[MI][4];
#pragma unroll
    for (int i = 0; i < MI; i++)
#pragma unroll
        for (int j = 0; j < 4; j++) acc[i][j] = (f32x4){0.f, 0.f, 0.f, 0.f};
    int nk = K >> 5;

    float4 fa[NC][2];  // in-flight f32 A (AF32 path)
    auto loadA = [&](int kt) {
#pragma unroll
        for (int c = 0; c < NC; ++c) {
            int o = c * 4096 + tid * 16;
            int row = o >> 6, e0 = (o & 63) >> 1;
            const float* src = (const float*)Ap + (size_t)(bi * BM + row) * K + kt * 32 + e0;
            fa[c][0] = *(const float4*)src;
            fa[c][1] = *(const float4*)(src + 4);
        }
    };
    auto writeA = [&](int buf) {
#pragma unroll
        for (int c = 0; c < NC; ++c) {
            int o = c * 4096 + tid * 16;
            u32 w0 = (u32)f2bf(fa[c][0].x) | ((u32)f2bf(fa[c][0].y) << 16);
            u32 w1 = (u32)f2bf(fa[c][0].z) | ((u32)f2bf(fa[c][0].w) << 16);
            u32 w2 = (u32)f2bf(fa[c][1].x) | ((u32)f2bf(fa[c][1].y) << 16);
            u32 w3 = (u32)f2bf(fa[c][1].z) | ((u32)f2bf(fa[c][1].w) << 16);
            *(u32x4*)((char*)(Al + buf * (BM * 32)) + o) = (u32x4){w0, w1, w2, w3};
        }
    };
    auto stageA_lds = [&](int buf, int kt) {
#pragma unroll
        for (int c = 0; c < NC; ++c) {
            int o = c * 4096 + tid * 16;
            int row = o >> 6, col = (o & 63) >> 1;
            gll16((const u16*)Ap + (size_t)(bi * BM + row) * K + kt * 32 + col,
                  (char*)(Al + buf * (BM * 32)) + o);
        }
    };
    auto stageB = [&](int buf, int kt) {
#pragma unroll
        for (int c = 0; c < 2; ++c) {
            int o = c * 4096 + tid * 16;
            int row = o >> 6, col = (o & 63) >> 1;
            gll16(Bm + (size_t)(bj * 128 + row) * K + kt * 32 + col, (char*)(Bl + buf * 4096) + o);
        }
    };

    if constexpr (AF32) { loadA(0); writeA(0); } else { stageA_lds(0, 0); }
    stageB(0, 0);
    __syncthreads();
    int cur = 0;
    for (int kt = 0; kt < nk; ++kt) {
        bool pre = (kt + 1 < nk);
        if (pre) {
            if constexpr (AF32) loadA(kt + 1); else stageA_lds(cur ^ 1, kt + 1);
            stageB(cur ^ 1, kt + 1);
        }
        bh8 av[MI], bv[4];
#pragma unroll
        for (int i = 0; i < MI; i++) av[i] = *(const bh8*)&Al[cur * (BM * 32) + (wm * (BM / 2) + i * 16 + ln) * 32 + hi * 8];
#pragma unroll
        for (int j = 0; j < 4; j++) bv[j] = *(const bh8*)&Bl[cur * 4096 + (wn * 64 + j * 16 + ln) * 32 + hi * 8];
#pragma unroll
        for (int i = 0; i < MI; i++)
#pragma unroll
            for (int j = 0; j < 4; j++)
                acc[i][j] = __builtin_amdgcn_mfma_f32_16x16x32_bf16(av[i], bv[j], acc[i][j], 0, 0, 0);
        if constexpr (AF32) { if (pre) writeA(cur ^ 1); }
        __syncthreads();
        cur ^= 1;
    }
    if constexpr (OBF == 2) {
        // V projection: write C^T into VT[b,h,d,s] via LDS transpose (reuses Al+Bl = 32KB)
#pragma unroll
        for (int j = 0; j < 4; j++) {
            int col = wn * 64 + j * 16 + ln;  // local d_model col 0..127
            float bvs = bias[bj * 128 + col];
#pragma unroll
            for (int i = 0; i < MI; i++) {
                int row0 = wm * (BM / 2) + i * 16 + hi * 4;  // local s row
                u32 p01 = (u32)f2bf(acc[i][j][0] + bvs) | ((u32)f2bf(acc[i][j][1] + bvs) << 16);
                u32 p23 = (u32)f2bf(acc[i][j][2] + bvs) | ((u32)f2bf(acc[i][j][3] + bvs) << 16);
                int idx = col * 128 + (row0 ^ ((col & 7) << 3));
                *(u32x2*)&Al[idx] = (u32x2){p01, p23};
            }
        }
        __syncthreads();
        int b = bi >> 4;
        int sbase = (bi & 15) * 128;
#pragma unroll
        for (int it = 0; it < 8; ++it) {
            int idx = it * 256 + tid;
            int dcol = idx >> 4;           // 0..127
            int sl = (idx & 15) * 8;       // 0..120
            bh8 v = *(const bh8*)&Al[dcol * 128 + (sl ^ ((dcol & 7) << 3))];
            int h = bj * 2 + (dcol >> 6), d = dcol & 63;
            *(bh8*)((u16*)Cv + ((size_t)((b * 16 + h) * 64 + d)) * 2048 + sbase + sl) = v;
        }
        return;
    }
#pragma unroll
    for (int j = 0; j < 4; j++) {
        int col = bj * 128 + wn * 64 + j * 16 + ln;
        float bvs = bias[col];
#pragma unroll
        for (int i = 0; i < MI; i++) {
            int row0 = bi * BM + wm * (BM / 2) + i * 16 + hi * 4;
#pragma unroll
            for (int rr = 0; rr < 4; rr++) {
                if (OBF) {
                    float v = (acc[i][j][rr] + bvs) * oscale;  // Q-proj folds softmax scale here
                    ((u16*)Cv)[(size_t)(row0 + rr) * N + col] = f2bf(v);
                } else {
                    ((float*)Cv)[(size_t)(row0 + rr) * N + col] = acc[i][j][rr] + bvs;
                }
            }
        }
    }
}

// fused QKV projections, A pre-converted to bf16: grid 768 (XCD-swizzled); z==2 (V) writes VT
__global__ __launch_bounds__(256, 3) void gemm_qkv(const u16* __restrict__ A0, const u16* __restrict__ A1,
                                                   const u16* __restrict__ A2, const u16* __restrict__ B0,
                                                   const u16* __restrict__ B1, const u16* __restrict__ B2,
                                                   const float* __restrict__ c0, const float* __restrict__ c1,
                                                   const float* __restrict__ c2, u16* __restrict__ C0,
                                                   u16* __restrict__ C1, u16* __restrict__ VT) {
    __shared__ short SH[16384];  // 32KB: Al(16KB) + Bl(16KB); reused whole for V transpose
    short* Al = SH;
    short* Bl = SH + 8192;
    int bid = blockIdx.x;
    int swz = (bid & 7) * 96 + (bid >> 3);
    int z = swz >> 8, t = swz & 255;
    if (z == 2) {
        gemm_body<128, 2, 0>(A2, B2, c2, VT, 1024, 1024, t >> 3, t & 7, Al, Bl, 1.0f);
    } else if (z == 0) {
        gemm_body<128, 1, 0>(A0, B0, c0, C0, 1024, 1024, t >> 3, t & 7, Al, Bl, 0.18033688f);
    } else {
        gemm_body<128, 1, 0>(A1, B1, c1, C1, 1024, 1024, t >> 3, t & 7, Al, Bl, 1.0f);
    }
}

// ---------------- output projection + residual: 64x128 tile, 8 waves --------------------
// R11: epilogue adds the residual (Qs) so ln_res reads a single input (48->32MB traffic).
__global__ __launch_bounds__(512, 4) void gemm_o(const u16* __restrict__ A, const u16* __restrict__ Bm,
                                                 const float* __restrict__ bias, const float* __restrict__ Res,
                                                 float* __restrict__ C) {
    __shared__ short Al[2 * 64 * 32];    // 8KB
    __shared__ short Bl[2 * 128 * 32];   // 16KB
    int tid = threadIdx.x, lane = tid & 63, w = tid >> 6;
    int ln = lane & 15, hi = lane >> 4;
    int wm = w >> 2, wn = w & 3;
    int bid = blockIdx.x;
    int swz = (bid & 7) * 64 + (bid >> 3);
    int bi = swz >> 3, bj = swz & 7;
    f32x4 acc[2][2];
#pragma unroll
    for (int i = 0; i < 2; i++)
#pragma unroll
        for (int j = 0; j < 2; j++) acc[i][j] = (f32x4){0.f, 0.f, 0.f, 0.f};

    auto stageA = [&](int buf, int kt) {
        if (tid < 256) {                     // waves 0-3 (wave-uniform predicate)
            int o = tid * 16;                // 256 x 16B = 4KB = 64x32 bf16
            int row = o >> 6, col = (o & 63) >> 1;
            gll16(A + (size_t)(bi * 64 + row) * 1024 + kt * 32 + col, (char*)(Al + buf * 2048) + o);
        }
    };
    auto stageB = [&](int buf, int kt) {
        int o = tid * 16;                    // 512 x 16B = 8KB = 128x32 bf16
        int row = o >> 6, col = (o & 63) >> 1;
        gll16(Bm + (size_t)(bj * 128 + row) * 1024 + kt * 32 + col, (char*)(Bl + buf * 4096) + o);
    };

    stageA(0, 0);
    stageB(0, 0);
    __syncthreads();
    int cur = 0;
    for (int kt = 0; kt < 32; ++kt) {
        if (kt + 1 < 32) {
            stageA(cur ^ 1, kt + 1);
            stageB(cur ^ 1, kt + 1);
        }
        bh8 av[2], bv[2];
#pragma unroll
        for (int i = 0; i < 2; i++) av[i] = *(const bh8*)&Al[cur * 2048 + (wm * 32 + i * 16 + ln) * 32 + hi * 8];
#pragma unroll
        for (int j = 0; j < 2; j++) bv[j] = *(const bh8*)&Bl[cur * 4096 + (wn * 32 + j * 16 + ln) * 32 + hi * 8];
#pragma unroll
        for (int i = 0; i < 2; i++)
#pragma unroll
            for (int j = 0; j < 2; j++)
                acc[i][j] = __builtin_amdgcn_mfma_f32_16x16x32_bf16(av[i], bv[j], acc[i][j], 0, 0, 0);
        __syncthreads();
        cur ^= 1;
    }
#pragma unroll
    for (int j = 0; j < 2; j++) {
        int col = bj * 128 + wn * 32 + j * 16 + ln;
        float bvs = bias[col];
#pragma unroll
        for (int i = 0; i < 2; i++) {
            int row0 = bi * 64 + wm * 32 + i * 16 + hi * 4;
#pragma unroll
            for (int rr = 0; rr < 4; rr++) {
                size_t idx = (size_t)(row0 + rr) * 1024 + col;
                C[idx] = acc[i][j][rr] + bvs + Res[idx];
            }
        }
    }
}

// ------- flash attention (causal): intra-block split-KV + 2-TILE UNROLL (R11) ------------
// R6 model: per block-step the three pipes run SERIALLY (MFMA 1380 + VALU 1500 + DS 2690
// ~= 5576 cy measured) because every wave is phase-locked by the per-tile barrier. R11
// unrolls 2 kv-tiles per barrier interval (T15 "att[2]" mechanism, +7-11% in m214):
// source order QK(t0),QK(t1) -> SM(t0),PV(t0) -> SM(t1),PV(t1) lets QK(t1) MFMAs issue
// under SM(t0) VALU and PV(t0) MFMAs under SM(t1) VALU. Per-wave P buffer reused
// sequentially (in-order DS: PV(t0) reads retire before SM(t1) writes). 4 staging buffers
// per group (pairs {0,1}/{2,3} alternate per step). LDS = 64+64+32 = 160KB exactly
// (AITER fmha precedent: 160KB/workgroup launches on gfx950). Same barrier count per
// group (same nh) -> no divergence hazard. Split/combine epilogue unchanged from R6.
template <int PLO, int PHI>
static __device__ __forceinline__ void attn_core(const u16* __restrict__ Qp, const u16* __restrict__ Kp,
                                                 const u16* __restrict__ VT, u16* __restrict__ Ctx,
                                                 short* Klb, short* Vlb, short* Pw, float* Csh, float* Ls,
                                                 int b, int h, int bh, int qt, int tid) {
    int lane = tid & 63, w = tid >> 6;       // w 0..7
    int grp = w >> 2;                        // kv chunk group
    int qsub = w & 3;                        // q-slot within group (32 rows each)
    int tgl = tid & 255;                     // thread id within group
    int ln = lane & 15, hi = lane >> 4;
    __builtin_amdgcn_s_setprio(PLO);
    bh8 ones;
#pragma unroll
    for (int e = 0; e < 8; e++) ones[e] = (short)0x3F80;  // bf16 1.0

    // per-group staging: Klb/Vlb point at this group's area (4 x 8KB buffers each)
    auto stage_kv = [&](int buf, int kt) {
#pragma unroll
        for (int c = 0; c < 2; ++c) {
            int o = c * 4096 + tgl * 16;     // 256 threads x 2 x 16B = 8KB per matrix
            int rr = o >> 7;
            int slot = (o >> 4) & 7;
            gll16(Kp + ((size_t)(b * S_LEN + kt * 64 + rr)) * DMODEL + h * DHD + ((slot ^ (rr & 7)) << 3),
                  (char*)(Klb + buf * 4096) + o);
            gll16(VT + ((size_t)(bh * DHD + rr)) * S_LEN + kt * 64 + ((slot ^ (rr & 7)) << 3),
                  (char*)(Vlb + buf * 4096) + o);
        }
    };

    int nh = qt + 1;                         // tiles per group
    int nt = 2 * qt + 2;                     // total causal kv tiles
    int kbase = grp * nh;
    int qg0 = (qt << 7) + qsub * 32 + ln;    // q-group 0 row; group 1 = qg0 + 16
    const bh8* qr0 = (const bh8*)(Qp + ((size_t)(b * S_LEN + qg0)) * DMODEL + h * DHD);
    const bh8* qr1 = (const bh8*)(Qp + ((size_t)(b * S_LEN + qg0 + 16)) * DMODEL + h * DHD);
    bh8 qf[2][2];
    qf[0][0] = qr0[hi]; qf[0][1] = qr0[4 + hi];
    qf[1][0] = qr1[hi]; qf[1][1] = qr1[4 + hi];
    f32x4 ctxa[2][4];
    f32x4 lacc[2];
#pragma unroll
    for (int g = 0; g < 2; g++) {
        lacc[g] = (f32x4){0.f, 0.f, 0.f, 0.f};
#pragma unroll
        for (int i = 0; i < 4; i++) ctxa[g][i] = (f32x4){0.f, 0.f, 0.f, 0.f};
    }
    stage_kv(0, kbase);
    if (nh > 1) stage_kv(1, kbase + 1);
    __syncthreads();
    for (int i = 0; i < nh; i += 2) {
        int s = i >> 1;
        int b0 = (s & 1) << 1;               // buffer pair {0,1} / {2,3} alternating
        int b1 = b0 + 1;
        bool two = (i + 1 < nh);
        if (i + 2 < nh) stage_kv(b0 ^ 2, kbase + i + 2);
        if (i + 3 < nh) stage_kv(b1 ^ 2, kbase + i + 3);
        int kt0 = kbase + i;
        int kt1 = kbase + i + 1;
        f32x4 scA[2][4], scB[2][4];
#pragma unroll
        for (int g = 0; g < 2; g++)
#pragma unroll
            for (int ks = 0; ks < 4; ++ks) { scA[g][ks] = (f32x4){0.f, 0.f, 0.f, 0.f}; scB[g][ks] = (f32x4){0.f, 0.f, 0.f, 0.f}; }
        // QK for both tiles first: QK(t1) MFMAs can issue while SM(t0) runs on VALU
        __builtin_amdgcn_s_setprio(PHI);
#pragma unroll
        for (int dwin = 0; dwin < 2; ++dwin) {
#pragma unroll
            for (int ks = 0; ks < 4; ++ks) {
                int rr = ks * 16 + ln;
                bh8 kv = *(const bh8*)&Klb[b0 * 4096 + rr * 64 + ((dwin * 32 + hi * 8) ^ ((rr & 7) << 3))];
                scA[0][ks] = __builtin_amdgcn_mfma_f32_16x16x32_bf16(kv, qf[0][dwin], scA[0][ks], 0, 0, 0);
                scA[1][ks] = __builtin_amdgcn_mfma_f32_16x16x32_bf16(kv, qf[1][dwin], scA[1][ks], 0, 0, 0);
            }
        }
        if (two) {
#pragma unroll
            for (int dwin = 0; dwin < 2; ++dwin) {
#pragma unroll
                for (int ks = 0; ks < 4; ++ks) {
                    int rr = ks * 16 + ln;
                    bh8 kv = *(const bh8*)&Klb[b1 * 4096 + rr * 64 + ((dwin * 32 + hi * 8) ^ ((rr & 7) << 3))];
                    scB[0][ks] = __builtin_amdgcn_mfma_f32_16x16x32_bf16(kv, qf[0][dwin], scB[0][ks], 0, 0, 0);
                    scB[1][ks] = __builtin_amdgcn_mfma_f32_16x16x32_bf16(kv, qf[1][dwin], scB[1][ks], 0, 0, 0);
                }
            }
        }
        __builtin_amdgcn_s_setprio(PLO);
        if (kt0 >= nt - 2) {
#pragma unroll
            for (int g = 0; g < 2; g++) {
                int qgq = qg0 + g * 16;
#pragma unroll
                for (int ks = 0; ks < 4; ++ks)
#pragma unroll
                    for (int rr = 0; rr < 4; ++rr) {
                        int kg = kt0 * 64 + ks * 16 + hi * 4 + rr;
                        scA[g][ks][rr] = (kg <= qgq) ? scA[g][ks][rr] : -1e30f;
                    }
            }
        }
        // ---- tile 0: softmax -> P -> PV ----
#pragma unroll
        for (int g = 0; g < 2; g++) {
#pragma unroll
            for (int ks = 0; ks < 4; ++ks) {
                u32 u0 = __builtin_bit_cast(u32, __builtin_amdgcn_exp2f(scA[g][ks][0]));
                u32 u1 = __builtin_bit_cast(u32, __builtin_amdgcn_exp2f(scA[g][ks][1]));
                u32 u2 = __builtin_bit_cast(u32, __builtin_amdgcn_exp2f(scA[g][ks][2]));
                u32 u3 = __builtin_bit_cast(u32, __builtin_amdgcn_exp2f(scA[g][ks][3]));
                u32 a01 = (u0 >> 16) | (u1 & 0xffff0000u);   // truncating bf16 pack
                u32 a23 = (u2 >> 16) | (u3 & 0xffff0000u);
                int kloc = ks * 16 + hi * 4;
                *(u32x2*)&Pw[(g * 16 + ln) * 64 + (kloc ^ ((ln & 7) << 3))] = (u32x2){a01, a23};
            }
        }
        __builtin_amdgcn_s_setprio(PHI);
#pragma unroll
        for (int kw = 0; kw < 2; ++kw) {
            bh8 pf0 = *(const bh8*)&Pw[ln * 64 + ((kw * 32 + hi * 8) ^ ((ln & 7) << 3))];
            bh8 pf1 = *(const bh8*)&Pw[(16 + ln) * 64 + ((kw * 32 + hi * 8) ^ ((ln & 7) << 3))];
            lacc[0] = __builtin_amdgcn_mfma_f32_16x16x32_bf16(ones, pf0, lacc[0], 0, 0, 0);
            lacc[1] = __builtin_amdgcn_mfma_f32_16x16x32_bf16(ones, pf1, lacc[1], 0, 0, 0);
#pragma unroll
            for (int ds = 0; ds < 4; ++ds) {
                int d = ds * 16 + ln;
                bh8 vf = *(const bh8*)&Vlb[b0 * 4096 + d * 64 + ((kw * 32 + hi * 8) ^ ((d & 7) << 3))];
                ctxa[0][ds] = __builtin_amdgcn_mfma_f32_16x16x32_bf16(vf, pf0, ctxa[0][ds], 0, 0, 0);
                ctxa[1][ds] = __builtin_amdgcn_mfma_f32_16x16x32_bf16(vf, pf1, ctxa[1][ds], 0, 0, 0);
            }
        }
        __builtin_amdgcn_s_setprio(PLO);
        // ---- tile 1: softmax -> P -> PV (in-order DS: PV(t0) reads retire first) ----
        if (two) {
            if (kt1 >= nt - 2) {
#pragma unroll
                for (int g = 0; g < 2; g++) {
                    int qgq = qg0 + g * 16;
#pragma unroll
                    for (int ks = 0; ks < 4; ++ks)
#pragma unroll
                        for (int rr = 0; rr < 4; ++rr) {
                            int kg = kt1 * 64 + ks * 16 + hi * 4 + rr;
                            scB[g][ks][rr] = (kg <= qgq) ? scB[g][ks][rr] : -1e30f;
                        }
                }
            }
#pragma unroll
            for (int g = 0; g < 2; g++) {
#pragma unroll
                for (int ks = 0; ks < 4; ++ks) {
                    u32 u0 = __builtin_bit_cast(u32, __builtin_amdgcn_exp2f(scB[g][ks][0]));
                    u32 u1 = __builtin_bit_cast(u32, __builtin_amdgcn_exp2f(scB[g][ks][1]));
                    u32 u2 = __builtin_bit_cast(u32, __builtin_amdgcn_exp2f(scB[g][ks][2]));
                    u32 u3 = __builtin_bit_cast(u32, __builtin_amdgcn_exp2f(scB[g][ks][3]));
                    u32 a01 = (u0 >> 16) | (u1 & 0xffff0000u);
                    u32 a23 = (u2 >> 16) | (u3 & 0xffff0000u);
                    int kloc = ks * 16 + hi * 4;
                    *(u32x2*)&Pw[(g * 16 + ln) * 64 + (kloc ^ ((ln & 7) << 3))] = (u32x2){a01, a23};
                }
            }
            __builtin_amdgcn_s_setprio(PHI);
#pragma unroll
            for (int kw = 0; kw < 2; ++kw) {
                bh8 pf0 = *(const bh8*)&Pw[ln * 64 + ((kw * 32 + hi * 8) ^ ((ln & 7) << 3))];
                bh8 pf1 = *(const bh8*)&Pw[(16 + ln) * 64 + ((kw * 32 + hi * 8) ^ ((ln & 7) << 3))];
                lacc[0] = __builtin_amdgcn_mfma_f32_16x16x32_bf16(ones, pf0, lacc[0], 0, 0, 0);
                lacc[1] = __builtin_amdgcn_mfma_f32_16x16x32_bf16(ones, pf1, lacc[1], 0, 0, 0);
#pragma unroll
                for (int ds = 0; ds < 4; ++ds) {
                    int d = ds * 16 + ln;
                    bh8 vf = *(const bh8*)&Vlb[b1 * 4096 + d * 64 + ((kw * 32 + hi * 8) ^ ((d & 7) << 3))];
                    ctxa[0][ds] = __builtin_amdgcn_mfma_f32_16x16x32_bf16(vf, pf0, ctxa[0][ds], 0, 0, 0);
                    ctxa[1][ds] = __builtin_amdgcn_mfma_f32_16x16x32_bf16(vf, pf1, ctxa[1][ds], 0, 0, 0);
                }
            }
            __builtin_amdgcn_s_setprio(PLO);
        }
        __syncthreads();
    }
    __builtin_amdgcn_s_setprio(0);
    // ---- intra-block combine: grp1 -> LDS, barrier, grp0 adds + normalizes + writes ----
    if (grp == 1) {
#pragma unroll
        for (int g = 0; g < 2; g++) {
            int qloc = g * 16 + ln;
#pragma unroll
            for (int ds = 0; ds < 4; ++ds) {
                int doff = (ds * 16 + hi * 4) ^ ((qloc & 7) << 3);  // bank-spread swizzle
                *(f32x4*)&Csh[(qsub * 32 + qloc) * 64 + doff] = ctxa[g][ds];
            }
            if (hi == 0) Ls[qsub * 32 + qloc] = lacc[g][0];
        }
    }
    __syncthreads();
    if (grp == 0) {
#pragma unroll
        for (int g = 0; g < 2; g++) {
            int qloc = g * 16 + ln;
            float inv = 1.f / (lacc[g][0] + Ls[qsub * 32 + qloc]);
            u16* cp = Ctx + ((size_t)(b * S_LEN + qg0 + g * 16)) * DMODEL + h * DHD;
#pragma unroll
            for (int ds = 0; ds < 4; ++ds) {
                int doff = (ds * 16 + hi * 4) ^ ((qloc & 7) << 3);
                f32x4 p = *(const f32x4*)&Csh[(qsub * 32 + qloc) * 64 + doff];
                ushort4 st;
                st.x = f2bf((ctxa[g][ds][0] + p[0]) * inv);
                st.y = f2bf((ctxa[g][ds][1] + p[1]) * inv);
                st.z = f2bf((ctxa[g][ds][2] + p[2]) * inv);
                st.w = f2bf((ctxa[g][ds][3] + p[3]) * inv);
                *(ushort4*)(cp + ds * 16 + hi * 4) = st;
            }
        }
    }
}

__global__ __launch_bounds__(512, 1) void attn_fwd(const u16* __restrict__ Qp, const u16* __restrict__ Kp,
                                                   const u16* __restrict__ VT, u16* __restrict__ Ctx) {
    __shared__ short Kl[2][4][4096];   // [grp][buf] 64KB
    __shared__ short Vl[2][4][4096];   // 64KB
    __shared__ short Pl[8][2048];      // per-wave 32x64 P, 32KB  (total = 160KB exactly)
    int tid = threadIdx.x, w = tid >> 6;
    int grp = w >> 2;
    int bid = blockIdx.x;
    int rnd = bid >> 8, slot = bid & 255;
    int xcd = slot & 7, t = slot >> 3;       // t 0..31
    int bh = xcd * 4 + (t & 3);              // bh pinned to XCD both rounds (K/V L2)
    int qte = t >> 2;                        // 0..7
    int qt = rnd ? (15 - 2 * qte) : (2 * qte);  // rnd0: evens asc; rnd1: odds desc (greedy pairing)
    int b = bh >> 4, h = bh & 15;
    float* Csh = (float*)&Kl[0][0][0];       // 32KB combine buffer (staging dead by then)
    float* Ls = (float*)&Pl[7][1024];        // 512B l-partials in grp1's dead P region
    if (qt >= 8)
        attn_core<2, 3>(Qp, Kp, VT, Ctx, &Kl[grp][0][0], &Vl[grp][0][0], &Pl[w][0], Csh, Ls, b, h, bh, qt, tid);
    else
        attn_core<0, 1>(Qp, Kp, VT, Ctx, &Kl[grp][0][0], &Vl[grp][0][0], &Pl[w][0], Csh, Ls, b, h, bh, qt, tid);
}

// ---------------- LayerNorm (input already includes residual, from gemm_o) ---------------
__global__ __launch_bounds__(256) void ln_res(const float* __restrict__ Y,
                                              const float* __restrict__ gamma, const float* __restrict__ beta,
                                              float* __restrict__ out) {
    int row = blockIdx.x, tid = threadIdx.x;
    const float4* yr = (const float4*)(Y + (size_t)row * DMODEL);
    float4 a = yr[tid];
    float x0 = a.x, x1 = a.y, x2 = a.z, x3 = a.w;
    float s1 = x0 + x1 + x2 + x3;
    float s2 = x0 * x0 + x1 * x1 + x2 * x2 + x3 * x3;
#pragma unroll
    for (int off = 32; off > 0; off >>= 1) {
        s1 += __shfl_xor(s1, off);
        s2 += __shfl_xor(s2, off);
    }
    __shared__ float r1[4], r2[4];
    int wv = tid >> 6;
    if ((tid & 63) == 0) { r1[wv] = s1; r2[wv] = s2; }
    __syncthreads();
    s1 = r1[0] + r1[1] + r1[2] + r1[3];
    s2 = r2[0] + r2[1] + r2[2] + r2[3];
    float mu = s1 * (1.0f / 1024.0f);
    float var = s2 * (1.0f / 1024.0f) - mu * mu;
    float rstd = rsqrtf(var + 1e-5f);
    const float4* g4 = (const float4*)gamma;
    const float4* b4 = (const float4*)beta;
    float4 g = g4[tid], bb = b4[tid];
    float4 res;
    res.x = (x0 - mu) * rstd * g.x + bb.x;
    res.y = (x1 - mu) * rstd * g.y + bb.y;
    res.z = (x2 - mu) * rstd * g.z + bb.z;
    res.w = (x3 - mu) * rstd * g.w + bb.w;
    *((float4*)(out + (size_t)row * DMODEL) + tid) = res;
}

extern "C" void kernel_launch(void* const* d_in, const int* in_sizes, int n_in,
                              void* d_out, int out_size, void* d_ws, size_t ws_size,
                              hipStream_t stream) {
    const float* Qs = (const float*)d_in[0];
    const float* Ks = (const float*)d_in[1];
    const float* Vs = (const float*)d_in[2];
    const float* WQ = (const float*)d_in[5];
    const float* bQ = (const float*)d_in[6];
    const float* WK = (const float*)d_in[7];
    const float* bK = (const float*)d_in[8];
    const float* WV = (const float*)d_in[9];
    const float* bV = (const float*)d_in[10];
    const float* WO = (const float*)d_in[11];
    const float* bO = (const float*)d_in[12];
    const float* gamma = (const float*)d_in[13];
    const float* beta = (const float*)d_in[14];

    const size_t MB = 1u << 20;
    char* w8 = (char*)d_ws;
    u16* Qb  = (u16*)(w8 + 0 * MB);   // bf16 sources (8MB each)
    u16* Kb  = (u16*)(w8 + 8 * MB);
    u16* Vb  = (u16*)(w8 + 16 * MB);
    u16* WQb = (u16*)(w8 + 24 * MB);
    u16* WKb = (u16*)(w8 + 26 * MB);
    u16* WVb = (u16*)(w8 + 28 * MB);
    u16* WOb = (u16*)(w8 + 30 * MB);
    u16* Qp  = (u16*)(w8 + 32 * MB);
    u16* Kp  = (u16*)(w8 + 40 * MB);
    u16* VTb = (u16*)(w8 + 56 * MB);
    u16* Ctx = (u16*)(w8 + 64 * MB);
    float* Y2 = (float*)(w8 + 72 * MB);

    cvt_all<<<8192, 256, 0, stream>>>(WQ, WK, WV, WO, Qs, Ks, Vs, WQb, WKb, WVb, WOb, Qb, Kb, Vb);
    gemm_qkv<<<768, 256, 0, stream>>>(Qb, Kb, Vb, WQb, WKb, WVb, bQ, bK, bV, Qp, Kp, VTb);
    attn_fwd<<<512, 512, 0, stream>>>(Qp, Kp, VTb, Ctx);
    gemm_o<<<512, 512, 0, stream>>>(Ctx, WOb, bO, Qs, Y2);
    ln_res<<<4096, 256, 0, stream>>>(Y2, gamma, beta, (float*)d_out);
}

// Round 13
// 107.186 us; speedup vs baseline: 1.4338x; 1.0245x over previous
//
#include <hip/hip_runtime.h>

#define S_LEN 2048
#define DMODEL 1024
#define NH 16
#define DHD 64

typedef __attribute__((ext_vector_type(8))) short bh8;
typedef __attribute__((ext_vector_type(4))) float f32x4;
typedef __attribute__((ext_vector_type(2))) unsigned int u32x2;
typedef __attribute__((ext_vector_type(4))) unsigned int u32x4;
typedef unsigned short u16;
typedef unsigned int u32;

static __device__ __forceinline__ u16 f2bf(float f) {
    unsigned u = __builtin_bit_cast(unsigned, f);
    u += 0x7fffu + ((u >> 16) & 1u);
    return (u16)(u >> 16);
}

typedef const __attribute__((address_space(1))) void* gptr_t;
typedef __attribute__((address_space(3))) void* lptr_t;

static __device__ __forceinline__ void gll16(const void* g, void* l) {
    __builtin_amdgcn_global_load_lds((gptr_t)g, (lptr_t)l, 16, 0, 0);
}

// ---------------- convert fp32 -> bf16: weights (4x1M) + sources (3x4M) --------------
__global__ __launch_bounds__(256) void cvt_all(const float* __restrict__ WQ, const float* __restrict__ WK,
                                               const float* __restrict__ WV, const float* __restrict__ WO,
                                               const float* __restrict__ S0, const float* __restrict__ S1,
                                               const float* __restrict__ S2,
                                               u16* __restrict__ wq, u16* __restrict__ wk,
                                               u16* __restrict__ wv, u16* __restrict__ wo,
                                               u16* __restrict__ q0, u16* __restrict__ k0,
                                               u16* __restrict__ v0) {
    int bid = blockIdx.x;
    const float* s;
    u16* o;
    size_t base;
    if (bid < 2048) {
        int wi = bid >> 9;
        s = wi == 0 ? WQ : (wi == 1 ? WK : (wi == 2 ? WV : WO));
        o = wi == 0 ? wq : (wi == 1 ? wk : (wi == 2 ? wv : wo));
        base = (size_t)(bid & 511) * 2048;
    } else {
        int r = bid - 2048;
        int si = r >> 11;
        s = si == 0 ? S0 : (si == 1 ? S1 : S2);
        o = si == 0 ? q0 : (si == 1 ? k0 : v0);
        base = (size_t)(r & 2047) * 2048;
    }
    size_t i = base + (size_t)threadIdx.x * 8;
    float4 a = *(const float4*)(s + i);
    float4 b = *(const float4*)(s + i + 4);
    u32 p0 = (u32)f2bf(a.x) | ((u32)f2bf(a.y) << 16);
    u32 p1 = (u32)f2bf(a.z) | ((u32)f2bf(a.w) << 16);
    u32 p2 = (u32)f2bf(b.x) | ((u32)f2bf(b.y) << 16);
    u32 p3 = (u32)f2bf(b.z) | ((u32)f2bf(b.w) << 16);
    *(u32x4*)(o + i) = (u32x4){p0, p1, p2, p3};
}

// ---------------- GEMM body: C[M,N] = A[M,K]*B[N,K]^T + bias, 2-phase dbuf ----------------
template <int BM, int OBF, int AF32>
static __device__ __forceinline__ void gemm_body(const void* __restrict__ Ap, const u16* __restrict__ Bm,
                                                 const float* __restrict__ bias, void* __restrict__ Cv,
                                                 int N, int K, int bi, int bj, short* Al, short* Bl,
                                                 float oscale) {
    constexpr int MI = BM / 32;
    constexpr int NC = BM / 64;
    int tid = threadIdx.x, lane = tid & 63, w = tid >> 6;
    int ln = lane & 15, hi = lane >> 4;
    int wm = w >> 1, wn = w & 1;
    f32x4 acc[MI][4];
#pragma unroll
    for (int i = 0; i < MI; i++)
#pragma unroll
        for (int j = 0; j < 4; j++) acc[i][j] = (f32x4){0.f, 0.f, 0.f, 0.f};
    int nk = K >> 5;

    float4 fa[NC][2];  // in-flight f32 A (AF32 path)
    auto loadA = [&](int kt) {
#pragma unroll
        for (int c = 0; c < NC; ++c) {
            int o = c * 4096 + tid * 16;
            int row = o >> 6, e0 = (o & 63) >> 1;
            const float* src = (const float*)Ap + (size_t)(bi * BM + row) * K + kt * 32 + e0;
            fa[c][0] = *(const float4*)src;
            fa[c][1] = *(const float4*)(src + 4);
        }
    };
    auto writeA = [&](int buf) {
#pragma unroll
        for (int c = 0; c < NC; ++c) {
            int o = c * 4096 + tid * 16;
            u32 w0 = (u32)f2bf(fa[c][0].x) | ((u32)f2bf(fa[c][0].y) << 16);
            u32 w1 = (u32)f2bf(fa[c][0].z) | ((u32)f2bf(fa[c][0].w) << 16);
            u32 w2 = (u32)f2bf(fa[c][1].x) | ((u32)f2bf(fa[c][1].y) << 16);
            u32 w3 = (u32)f2bf(fa[c][1].z) | ((u32)f2bf(fa[c][1].w) << 16);
            *(u32x4*)((char*)(Al + buf * (BM * 32)) + o) = (u32x4){w0, w1, w2, w3};
        }
    };
    auto stageA_lds = [&](int buf, int kt) {
#pragma unroll
        for (int c = 0; c < NC; ++c) {
            int o = c * 4096 + tid * 16;
            int row = o >> 6, col = (o & 63) >> 1;
            gll16((const u16*)Ap + (size_t)(bi * BM + row) * K + kt * 32 + col,
                  (char*)(Al + buf * (BM * 32)) + o);
        }
    };
    auto stageB = [&](int buf, int kt) {
#pragma unroll
        for (int c = 0; c < 2; ++c) {
            int o = c * 4096 + tid * 16;
            int row = o >> 6, col = (o & 63) >> 1;
            gll16(Bm + (size_t)(bj * 128 + row) * K + kt * 32 + col, (char*)(Bl + buf * 4096) + o);
        }
    };

    if constexpr (AF32) { loadA(0); writeA(0); } else { stageA_lds(0, 0); }
    stageB(0, 0);
    __syncthreads();
    int cur = 0;
    for (int kt = 0; kt < nk; ++kt) {
        bool pre = (kt + 1 < nk);
        if (pre) {
            if constexpr (AF32) loadA(kt + 1); else stageA_lds(cur ^ 1, kt + 1);
            stageB(cur ^ 1, kt + 1);
        }
        bh8 av[MI], bv[4];
#pragma unroll
        for (int i = 0; i < MI; i++) av[i] = *(const bh8*)&Al[cur * (BM * 32) + (wm * (BM / 2) + i * 16 + ln) * 32 + hi * 8];
#pragma unroll
        for (int j = 0; j < 4; j++) bv[j] = *(const bh8*)&Bl[cur * 4096 + (wn * 64 + j * 16 + ln) * 32 + hi * 8];
#pragma unroll
        for (int i = 0; i < MI; i++)
#pragma unroll
            for (int j = 0; j < 4; j++)
                acc[i][j] = __builtin_amdgcn_mfma_f32_16x16x32_bf16(av[i], bv[j], acc[i][j], 0, 0, 0);
        if constexpr (AF32) { if (pre) writeA(cur ^ 1); }
        __syncthreads();
        cur ^= 1;
    }
    if constexpr (OBF == 2) {
        // V projection: write C^T into VT[b,h,d,s] via LDS transpose (reuses Al+Bl = 32KB)
#pragma unroll
        for (int j = 0; j < 4; j++) {
            int col = wn * 64 + j * 16 + ln;  // local d_model col 0..127
            float bvs = bias[bj * 128 + col];
#pragma unroll
            for (int i = 0; i < MI; i++) {
                int row0 = wm * (BM / 2) + i * 16 + hi * 4;  // local s row
                u32 p01 = (u32)f2bf(acc[i][j][0] + bvs) | ((u32)f2bf(acc[i][j][1] + bvs) << 16);
                u32 p23 = (u32)f2bf(acc[i][j][2] + bvs) | ((u32)f2bf(acc[i][j][3] + bvs) << 16);
                int idx = col * 128 + (row0 ^ ((col & 7) << 3));
                *(u32x2*)&Al[idx] = (u32x2){p01, p23};
            }
        }
        __syncthreads();
        int b = bi >> 4;
        int sbase = (bi & 15) * 128;
#pragma unroll
        for (int it = 0; it < 8; ++it) {
            int idx = it * 256 + tid;
            int dcol = idx >> 4;           // 0..127
            int sl = (idx & 15) * 8;       // 0..120
            bh8 v = *(const bh8*)&Al[dcol * 128 + (sl ^ ((dcol & 7) << 3))];
            int h = bj * 2 + (dcol >> 6), d = dcol & 63;
            *(bh8*)((u16*)Cv + ((size_t)((b * 16 + h) * 64 + d)) * 2048 + sbase + sl) = v;
        }
        return;
    }
#pragma unroll
    for (int j = 0; j < 4; j++) {
        int col = bj * 128 + wn * 64 + j * 16 + ln;
        float bvs = bias[col];
#pragma unroll
        for (int i = 0; i < MI; i++) {
            int row0 = bi * BM + wm * (BM / 2) + i * 16 + hi * 4;
#pragma unroll
            for (int rr = 0; rr < 4; rr++) {
                if (OBF) {
                    float v = (acc[i][j][rr] + bvs) * oscale;  // Q-proj folds softmax scale here
                    ((u16*)Cv)[(size_t)(row0 + rr) * N + col] = f2bf(v);
                } else {
                    ((float*)Cv)[(size_t)(row0 + rr) * N + col] = acc[i][j][rr] + bvs;
                }
            }
        }
    }
}

// fused QKV projections, A pre-converted to bf16: grid 768 (XCD-swizzled); z==2 (V) writes VT
__global__ __launch_bounds__(256, 3) void gemm_qkv(const u16* __restrict__ A0, const u16* __restrict__ A1,
                                                   const u16* __restrict__ A2, const u16* __restrict__ B0,
                                                   const u16* __restrict__ B1, const u16* __restrict__ B2,
                                                   const float* __restrict__ c0, const float* __restrict__ c1,
                                                   const float* __restrict__ c2, u16* __restrict__ C0,
                                                   u16* __restrict__ C1, u16* __restrict__ VT) {
    __shared__ short SH[16384];  // 32KB: Al(16KB) + Bl(16KB); reused whole for V transpose
    short* Al = SH;
    short* Bl = SH + 8192;
    int bid = blockIdx.x;
    int swz = (bid & 7) * 96 + (bid >> 3);
    int z = swz >> 8, t = swz & 255;
    if (z == 2) {
        gemm_body<128, 2, 0>(A2, B2, c2, VT, 1024, 1024, t >> 3, t & 7, Al, Bl, 1.0f);
    } else if (z == 0) {
        gemm_body<128, 1, 0>(A0, B0, c0, C0, 1024, 1024, t >> 3, t & 7, Al, Bl, 0.18033688f);
    } else {
        gemm_body<128, 1, 0>(A1, B1, c1, C1, 1024, 1024, t >> 3, t & 7, Al, Bl, 1.0f);
    }
}

// ---------------- output projection + residual: 64x128 tile, K-SPLIT 8 waves (R12) ------
// gemm_o was DS-bound: 8-wave acc[2][2] = 8 FLOP/LDS-byte (vs gemm_qkv's 16). R12 splits
// the 8 waves as 2 k-halves x 4 output waves; each wave owns 32x64 = acc[2][4] (10.9
// FLOP/B, -27% DS traffic) over K=512. Each half stages its own A/B slices (48KB LDS ->
// still 2 blocks/CU, 16 waves/CU); barrier count halves (16 k-steps). Epilogue = R6-style
// LDS combine: half-1 writes f32 partials (swizzled), barrier, half-0 adds+bias+residual.
__global__ __launch_bounds__(512, 4) void gemm_o(const u16* __restrict__ A, const u16* __restrict__ Bm,
                                                 const float* __restrict__ bias, const float* __restrict__ Res,
                                                 float* __restrict__ C) {
    __shared__ char SH[49152];           // Al 2x2x4KB (0..16K) + Bl 2x2x8KB (16K..48K)
    int tid = threadIdx.x, lane = tid & 63, w = tid >> 6;
    int ln = lane & 15, hi = lane >> 4;
    int kh = w >> 2;                     // k-half 0/1 (threads 0-255 / 256-511)
    int wq = w & 3;
    int wm = wq >> 1, wn = wq & 1;       // wave output 32 rows x 64 cols
    int tgl = tid & 255;
    int bid = blockIdx.x;
    int swz = (bid & 7) * 64 + (bid >> 3);
    int bi = swz >> 3, bj = swz & 7;
    f32x4 acc[2][4];
#pragma unroll
    for (int i = 0; i < 2; i++)
#pragma unroll
        for (int j = 0; j < 4; j++) acc[i][j] = (f32x4){0.f, 0.f, 0.f, 0.f};

    auto Alp = [&](int buf) { return (short*)(SH + kh * 8192 + buf * 4096); };
    auto Blp = [&](int buf) { return (short*)(SH + 16384 + kh * 16384 + buf * 8192); };
    auto stageA = [&](int buf, int kt) {
        int o = tgl * 16;                // 256 x 16B = 4KB = 64x32 bf16
        int row = o >> 6, col = (o & 63) >> 1;
        gll16(A + (size_t)(bi * 64 + row) * 1024 + kh * 512 + kt * 32 + col, (char*)Alp(buf) + o);
    };
    auto stageB = [&](int buf, int kt) {
#pragma unroll
        for (int c = 0; c < 2; ++c) {
            int o = c * 4096 + tgl * 16; // 8KB = 128x32 bf16
            int row = o >> 6, col = (o & 63) >> 1;
            gll16(Bm + (size_t)(bj * 128 + row) * 1024 + kh * 512 + kt * 32 + col, (char*)Blp(buf) + o);
        }
    };

    stageA(0, 0);
    stageB(0, 0);
    __syncthreads();
    int cur = 0;
    for (int kt = 0; kt < 16; ++kt) {
        if (kt + 1 < 16) {
            stageA(cur ^ 1, kt + 1);
            stageB(cur ^ 1, kt + 1);
        }
        bh8 av[2], bv[4];
#pragma unroll
        for (int i = 0; i < 2; i++) av[i] = *(const bh8*)&Alp(cur)[(wm * 32 + i * 16 + ln) * 32 + hi * 8];
#pragma unroll
        for (int j = 0; j < 4; j++) bv[j] = *(const bh8*)&Blp(cur)[(wn * 64 + j * 16 + ln) * 32 + hi * 8];
#pragma unroll
        for (int i = 0; i < 2; i++)
#pragma unroll
            for (int j = 0; j < 4; j++)
                acc[i][j] = __builtin_amdgcn_mfma_f32_16x16x32_bf16(av[i], bv[j], acc[i][j], 0, 0, 0);
        __syncthreads();
        cur ^= 1;
    }
    // ---- k-split combine: half-1 -> LDS (swizzled), barrier, half-0 finishes ----
    float* Csh = (float*)SH;             // 64x128 f32 = 32KB (staging dead)
    if (kh == 1) {
#pragma unroll
        for (int j = 0; j < 4; j++) {
            int col = wn * 64 + j * 16 + ln;
#pragma unroll
            for (int i = 0; i < 2; i++) {
                int r0 = wm * 32 + i * 16 + hi * 4;
                *(f32x4*)&Csh[col * 64 + (r0 ^ ((col & 7) << 2))] = acc[i][j];
            }
        }
    }
    __syncthreads();
    if (kh == 0) {
#pragma unroll
        for (int j = 0; j < 4; j++) {
            int col = wn * 64 + j * 16 + ln;
            int colg = bj * 128 + col;
            float bvs = bias[colg];
#pragma unroll
            for (int i = 0; i < 2; i++) {
                int r0 = wm * 32 + i * 16 + hi * 4;
                f32x4 p = *(const f32x4*)&Csh[col * 64 + (r0 ^ ((col & 7) << 2))];
#pragma unroll
                for (int rr = 0; rr < 4; rr++) {
                    size_t idx = (size_t)(bi * 64 + r0 + rr) * 1024 + colg;
                    C[idx] = acc[i][j][rr] + p[rr] + bvs + Res[idx];
                }
            }
        }
    }
}

// ------- flash attention (causal): intra-block split-KV + 2-TILE UNROLL (R11, frozen) ----
template <int PLO, int PHI>
static __device__ __forceinline__ void attn_core(const u16* __restrict__ Qp, const u16* __restrict__ Kp,
                                                 const u16* __restrict__ VT, u16* __restrict__ Ctx,
                                                 short* Klb, short* Vlb, short* Pw, float* Csh, float* Ls,
                                                 int b, int h, int bh, int qt, int tid) {
    int lane = tid & 63, w = tid >> 6;       // w 0..7
    int grp = w >> 2;                        // kv chunk group
    int qsub = w & 3;                        // q-slot within group (32 rows each)
    int tgl = tid & 255;                     // thread id within group
    int ln = lane & 15, hi = lane >> 4;
    __builtin_amdgcn_s_setprio(PLO);
    bh8 ones;
#pragma unroll
    for (int e = 0; e < 8; e++) ones[e] = (short)0x3F80;  // bf16 1.0

    // per-group staging: Klb/Vlb point at this group's area (4 x 8KB buffers each)
    auto stage_kv = [&](int buf, int kt) {
#pragma unroll
        for (int c = 0; c < 2; ++c) {
            int o = c * 4096 + tgl * 16;     // 256 threads x 2 x 16B = 8KB per matrix
            int rr = o >> 7;
            int slot = (o >> 4) & 7;
            gll16(Kp + ((size_t)(b * S_LEN + kt * 64 + rr)) * DMODEL + h * DHD + ((slot ^ (rr & 7)) << 3),
                  (char*)(Klb + buf * 4096) + o);
            gll16(VT + ((size_t)(bh * DHD + rr)) * S_LEN + kt * 64 + ((slot ^ (rr & 7)) << 3),
                  (char*)(Vlb + buf * 4096) + o);
        }
    };

    int nh = qt + 1;                         // tiles per group
    int nt = 2 * qt + 2;                     // total causal kv tiles
    int kbase = grp * nh;
    int qg0 = (qt << 7) + qsub * 32 + ln;    // q-group 0 row; group 1 = qg0 + 16
    const bh8* qr0 = (const bh8*)(Qp + ((size_t)(b * S_LEN + qg0)) * DMODEL + h * DHD);
    const bh8* qr1 = (const bh8*)(Qp + ((size_t)(b * S_LEN + qg0 + 16)) * DMODEL + h * DHD);
    bh8 qf[2][2];
    qf[0][0] = qr0[hi]; qf[0][1] = qr0[4 + hi];
    qf[1][0] = qr1[hi]; qf[1][1] = qr1[4 + hi];
    f32x4 ctxa[2][4];
    f32x4 lacc[2];
#pragma unroll
    for (int g = 0; g < 2; g++) {
        lacc[g] = (f32x4){0.f, 0.f, 0.f, 0.f};
#pragma unroll
        for (int i = 0; i < 4; i++) ctxa[g][i] = (f32x4){0.f, 0.f, 0.f, 0.f};
    }
    stage_kv(0, kbase);
    if (nh > 1) stage_kv(1, kbase + 1);
    __syncthreads();
    for (int i = 0; i < nh; i += 2) {
        int s = i >> 1;
        int b0 = (s & 1) << 1;               // buffer pair {0,1} / {2,3} alternating
        int b1 = b0 + 1;
        bool two = (i + 1 < nh);
        if (i + 2 < nh) stage_kv(b0 ^ 2, kbase + i + 2);
        if (i + 3 < nh) stage_kv(b1 ^ 2, kbase + i + 3);
        int kt0 = kbase + i;
        int kt1 = kbase + i + 1;
        f32x4 scA[2][4], scB[2][4];
#pragma unroll
        for (int g = 0; g < 2; g++)
#pragma unroll
            for (int ks = 0; ks < 4; ++ks) { scA[g][ks] = (f32x4){0.f, 0.f, 0.f, 0.f}; scB[g][ks] = (f32x4){0.f, 0.f, 0.f, 0.f}; }
        // QK for both tiles first: QK(t1) MFMAs can issue while SM(t0) runs on VALU
        __builtin_amdgcn_s_setprio(PHI);
#pragma unroll
        for (int dwin = 0; dwin < 2; ++dwin) {
#pragma unroll
            for (int ks = 0; ks < 4; ++ks) {
                int rr = ks * 16 + ln;
                bh8 kv = *(const bh8*)&Klb[b0 * 4096 + rr * 64 + ((dwin * 32 + hi * 8) ^ ((rr & 7) << 3))];
                scA[0][ks] = __builtin_amdgcn_mfma_f32_16x16x32_bf16(kv, qf[0][dwin], scA[0][ks], 0, 0, 0);
                scA[1][ks] = __builtin_amdgcn_mfma_f32_16x16x32_bf16(kv, qf[1][dwin], scA[1][ks], 0, 0, 0);
            }
        }
        if (two) {
#pragma unroll
            for (int dwin = 0; dwin < 2; ++dwin) {
#pragma unroll
                for (int ks = 0; ks < 4; ++ks) {
                    int rr = ks * 16 + ln;
                    bh8 kv = *(const bh8*)&Klb[b1 * 4096 + rr * 64 + ((dwin * 32 + hi * 8) ^ ((rr & 7) << 3))];
                    scB[0][ks] = __builtin_amdgcn_mfma_f32_16x16x32_bf16(kv, qf[0][dwin], scB[0][ks], 0, 0, 0);
                    scB[1][ks] = __builtin_amdgcn_mfma_f32_16x16x32_bf16(kv, qf[1][dwin], scB[1][ks], 0, 0, 0);
                }
            }
        }
        __builtin_amdgcn_s_setprio(PLO);
        if (kt0 >= nt - 2) {
#pragma unroll
            for (int g = 0; g < 2; g++) {
                int qgq = qg0 + g * 16;
#pragma unroll
                for (int ks = 0; ks < 4; ++ks)
#pragma unroll
                    for (int rr = 0; rr < 4; ++rr) {
                        int kg = kt0 * 64 + ks * 16 + hi * 4 + rr;
                        scA[g][ks][rr] = (kg <= qgq) ? scA[g][ks][rr] : -1e30f;
                    }
            }
        }
        // ---- tile 0: softmax -> P -> PV ----
#pragma unroll
        for (int g = 0; g < 2; g++) {
#pragma unroll
            for (int ks = 0; ks < 4; ++ks) {
                u32 u0 = __builtin_bit_cast(u32, __builtin_amdgcn_exp2f(scA[g][ks][0]));
                u32 u1 = __builtin_bit_cast(u32, __builtin_amdgcn_exp2f(scA[g][ks][1]));
                u32 u2 = __builtin_bit_cast(u32, __builtin_amdgcn_exp2f(scA[g][ks][2]));
                u32 u3 = __builtin_bit_cast(u32, __builtin_amdgcn_exp2f(scA[g][ks][3]));
                u32 a01 = (u0 >> 16) | (u1 & 0xffff0000u);   // truncating bf16 pack
                u32 a23 = (u2 >> 16) | (u3 & 0xffff0000u);
                int kloc = ks * 16 + hi * 4;
                *(u32x2*)&Pw[(g * 16 + ln) * 64 + (kloc ^ ((ln & 7) << 3))] = (u32x2){a01, a23};
            }
        }
        __builtin_amdgcn_s_setprio(PHI);
#pragma unroll
        for (int kw = 0; kw < 2; ++kw) {
            bh8 pf0 = *(const bh8*)&Pw[ln * 64 + ((kw * 32 + hi * 8) ^ ((ln & 7) << 3))];
            bh8 pf1 = *(const bh8*)&Pw[(16 + ln) * 64 + ((kw * 32 + hi * 8) ^ ((ln & 7) << 3))];
            lacc[0] = __builtin_amdgcn_mfma_f32_16x16x32_bf16(ones, pf0, lacc[0], 0, 0, 0);
            lacc[1] = __builtin_amdgcn_mfma_f32_16x16x32_bf16(ones, pf1, lacc[1], 0, 0, 0);
#pragma unroll
            for (int ds = 0; ds < 4; ++ds) {
                int d = ds * 16 + ln;
                bh8 vf = *(const bh8*)&Vlb[b0 * 4096 + d * 64 + ((kw * 32 + hi * 8) ^ ((d & 7) << 3))];
                ctxa[0][ds] = __builtin_amdgcn_mfma_f32_16x16x32_bf16(vf, pf0, ctxa[0][ds], 0, 0, 0);
                ctxa[1][ds] = __builtin_amdgcn_mfma_f32_16x16x32_bf16(vf, pf1, ctxa[1][ds], 0, 0, 0);
            }
        }
        __builtin_amdgcn_s_setprio(PLO);
        // ---- tile 1: softmax -> P -> PV (in-order DS: PV(t0) reads retire first) ----
        if (two) {
            if (kt1 >= nt - 2) {
#pragma unroll
                for (int g = 0; g < 2; g++) {
                    int qgq = qg0 + g * 16;
#pragma unroll
                    for (int ks = 0; ks < 4; ++ks)
#pragma unroll
                        for (int rr = 0; rr < 4; ++rr) {
                            int kg = kt1 * 64 + ks * 16 + hi * 4 + rr;
                            scB[g][ks][rr] = (kg <= qgq) ? scB[g][ks][rr] : -1e30f;
                        }
                }
            }
#pragma unroll
            for (int g = 0; g < 2; g++) {
#pragma unroll
                for (int ks = 0; ks < 4; ++ks) {
                    u32 u0 = __builtin_bit_cast(u32, __builtin_amdgcn_exp2f(scB[g][ks][0]));
                    u32 u1 = __builtin_bit_cast(u32, __builtin_amdgcn_exp2f(scB[g][ks][1]));
                    u32 u2 = __builtin_bit_cast(u32, __builtin_amdgcn_exp2f(scB[g][ks][2]));
                    u32 u3 = __builtin_bit_cast(u32, __builtin_amdgcn_exp2f(scB[g][ks][3]));
                    u32 a01 = (u0 >> 16) | (u1 & 0xffff0000u);
                    u32 a23 = (u2 >> 16) | (u3 & 0xffff0000u);
                    int kloc = ks * 16 + hi * 4;
                    *(u32x2*)&Pw[(g * 16 + ln) * 64 + (kloc ^ ((ln & 7) << 3))] = (u32x2){a01, a23};
                }
            }
            __builtin_amdgcn_s_setprio(PHI);
#pragma unroll
            for (int kw = 0; kw < 2; ++kw) {
                bh8 pf0 = *(const bh8*)&Pw[ln * 64 + ((kw * 32 + hi * 8) ^ ((ln & 7) << 3))];
                bh8 pf1 = *(const bh8*)&Pw[(16 + ln) * 64 + ((kw * 32 + hi * 8) ^ ((ln & 7) << 3))];
                lacc[0] = __builtin_amdgcn_mfma_f32_16x16x32_bf16(ones, pf0, lacc[0], 0, 0, 0);
                lacc[1] = __builtin_amdgcn_mfma_f32_16x16x32_bf16(ones, pf1, lacc[1], 0, 0, 0);
#pragma unroll
                for (int ds = 0; ds < 4; ++ds) {
                    int d = ds * 16 + ln;
                    bh8 vf = *(const bh8*)&Vlb[b1 * 4096 + d * 64 + ((kw * 32 + hi * 8) ^ ((d & 7) << 3))];
                    ctxa[0][ds] = __builtin_amdgcn_mfma_f32_16x16x32_bf16(vf, pf0, ctxa[0][ds], 0, 0, 0);
                    ctxa[1][ds] = __builtin_amdgcn_mfma_f32_16x16x32_bf16(vf, pf1, ctxa[1][ds], 0, 0, 0);
                }
            }
            __builtin_amdgcn_s_setprio(PLO);
        }
        __syncthreads();
    }
    __builtin_amdgcn_s_setprio(0);
    // ---- intra-block combine: grp1 -> LDS, barrier, grp0 adds + normalizes + writes ----
    if (grp == 1) {
#pragma unroll
        for (int g = 0; g < 2; g++) {
            int qloc = g * 16 + ln;
#pragma unroll
            for (int ds = 0; ds < 4; ++ds) {
                int doff = (ds * 16 + hi * 4) ^ ((qloc & 7) << 3);  // bank-spread swizzle
                *(f32x4*)&Csh[(qsub * 32 + qloc) * 64 + doff] = ctxa[g][ds];
            }
            if (hi == 0) Ls[qsub * 32 + qloc] = lacc[g][0];
        }
    }
    __syncthreads();
    if (grp == 0) {
#pragma unroll
        for (int g = 0; g < 2; g++) {
            int qloc = g * 16 + ln;
            float inv = 1.f / (lacc[g][0] + Ls[qsub * 32 + qloc]);
            u16* cp = Ctx + ((size_t)(b * S_LEN + qg0 + g * 16)) * DMODEL + h * DHD;
#pragma unroll
            for (int ds = 0; ds < 4; ++ds) {
                int doff = (ds * 16 + hi * 4) ^ ((qloc & 7) << 3);
                f32x4 p = *(const f32x4*)&Csh[(qsub * 32 + qloc) * 64 + doff];
                ushort4 st;
                st.x = f2bf((ctxa[g][ds][0] + p[0]) * inv);
                st.y = f2bf((ctxa[g][ds][1] + p[1]) * inv);
                st.z = f2bf((ctxa[g][ds][2] + p[2]) * inv);
                st.w = f2bf((ctxa[g][ds][3] + p[3]) * inv);
                *(ushort4*)(cp + ds * 16 + hi * 4) = st;
            }
        }
    }
}

__global__ __launch_bounds__(512, 1) void attn_fwd(const u16* __restrict__ Qp, const u16* __restrict__ Kp,
                                                   const u16* __restrict__ VT, u16* __restrict__ Ctx) {
    __shared__ short Kl[2][4][4096];   // [grp][buf] 64KB
    __shared__ short Vl[2][4][4096];   // 64KB
    __shared__ short Pl[8][2048];      // per-wave 32x64 P, 32KB  (total = 160KB exactly)
    int tid = threadIdx.x, w = tid >> 6;
    int grp = w >> 2;
    int bid = blockIdx.x;
    int rnd = bid >> 8, slot = bid & 255;
    int xcd = slot & 7, t = slot >> 3;       // t 0..31
    int bh = xcd * 4 + (t & 3);              // bh pinned to XCD both rounds (K/V L2)
    int qte = t >> 2;                        // 0..7
    int qt = rnd ? (15 - 2 * qte) : (2 * qte);  // rnd0: evens asc; rnd1: odds desc (greedy pairing)
    int b = bh >> 4, h = bh & 15;
    float* Csh = (float*)&Kl[0][0][0];       // 32KB combine buffer (staging dead by then)
    float* Ls = (float*)&Pl[7][1024];        // 512B l-partials in grp1's dead P region
    if (qt >= 8)
        attn_core<2, 3>(Qp, Kp, VT, Ctx, &Kl[grp][0][0], &Vl[grp][0][0], &Pl[w][0], Csh, Ls, b, h, bh, qt, tid);
    else
        attn_core<0, 1>(Qp, Kp, VT, Ctx, &Kl[grp][0][0], &Vl[grp][0][0], &Pl[w][0], Csh, Ls, b, h, bh, qt, tid);
}

// ---------------- LayerNorm (input already includes residual, from gemm_o) ---------------
__global__ __launch_bounds__(256) void ln_res(const float* __restrict__ Y,
                                              const float* __restrict__ gamma, const float* __restrict__ beta,
                                              float* __restrict__ out) {
    int row = blockIdx.x, tid = threadIdx.x;
    const float4* yr = (const float4*)(Y + (size_t)row * DMODEL);
    float4 a = yr[tid];
    float x0 = a.x, x1 = a.y, x2 = a.z, x3 = a.w;
    float s1 = x0 + x1 + x2 + x3;
    float s2 = x0 * x0 + x1 * x1 + x2 * x2 + x3 * x3;
#pragma unroll
    for (int off = 32; off > 0; off >>= 1) {
        s1 += __shfl_xor(s1, off);
        s2 += __shfl_xor(s2, off);
    }
    __shared__ float r1[4], r2[4];
    int wv = tid >> 6;
    if ((tid & 63) == 0) { r1[wv] = s1; r2[wv] = s2; }
    __syncthreads();
    s1 = r1[0] + r1[1] + r1[2] + r1[3];
    s2 = r2[0] + r2[1] + r2[2] + r2[3];
    float mu = s1 * (1.0f / 1024.0f);
    float var = s2 * (1.0f / 1024.0f) - mu * mu;
    float rstd = rsqrtf(var + 1e-5f);
    const float4* g4 = (const float4*)gamma;
    const float4* b4 = (const float4*)beta;
    float4 g = g4[tid], bb = b4[tid];
    float4 res;
    res.x = (x0 - mu) * rstd * g.x + bb.x;
    res.y = (x1 - mu) * rstd * g.y + bb.y;
    res.z = (x2 - mu) * rstd * g.z + bb.z;
    res.w = (x3 - mu) * rstd * g.w + bb.w;
    *((float4*)(out + (size_t)row * DMODEL) + tid) = res;
}

extern "C" void kernel_launch(void* const* d_in, const int* in_sizes, int n_in,
                              void* d_out, int out_size, void* d_ws, size_t ws_size,
                              hipStream_t stream) {
    const float* Qs = (const float*)d_in[0];
    const float* Ks = (const float*)d_in[1];
    const float* Vs = (const float*)d_in[2];
    const float* WQ = (const float*)d_in[5];
    const float* bQ = (const float*)d_in[6];
    const float* WK = (const float*)d_in[7];
    const float* bK = (const float*)d_in[8];
    const float* WV = (const float*)d_in[9];
    const float* bV = (const float*)d_in[10];
    const float* WO = (const float*)d_in[11];
    const float* bO = (const float*)d_in[12];
    const float* gamma = (const float*)d_in[13];
    const float* beta = (const float*)d_in[14];

    const size_t MB = 1u << 20;
    char* w8 = (char*)d_ws;
    u16* Qb  = (u16*)(w8 + 0 * MB);   // bf16 sources (8MB each)
    u16* Kb  = (u16*)(w8 + 8 * MB);
    u16* Vb  = (u16*)(w8 + 16 * MB);
    u16* WQb = (u16*)(w8 + 24 * MB);
    u16* WKb = (u16*)(w8 + 26 * MB);
    u16* WVb = (u16*)(w8 + 28 * MB);
    u16* WOb = (u16*)(w8 + 30 * MB);
    u16* Qp  = (u16*)(w8 + 32 * MB);
    u16* Kp  = (u16*)(w8 + 40 * MB);
    u16* VTb = (u16*)(w8 + 56 * MB);
    u16* Ctx = (u16*)(w8 + 64 * MB);
    float* Y2 = (float*)(w8 + 72 * MB);

    cvt_all<<<8192, 256, 0, stream>>>(WQ, WK, WV, WO, Qs, Ks, Vs, WQb, WKb, WVb, WOb, Qb, Kb, Vb);
    gemm_qkv<<<768, 256, 0, stream>>>(Qb, Kb, Vb, WQb, WKb, WVb, bQ, bK, bV, Qp, Kp, VTb);
    attn_fwd<<<512, 512, 0, stream>>>(Qp, Kp, VTb, Ctx);
    gemm_o<<<512, 512, 0, stream>>>(Ctx, WOb, bO, Qs, Y2);
    ln_res<<<4096, 256, 0, stream>>>(Y2, gamma, beta, (float*)d_out);
}

// Round 14
// 105.229 us; speedup vs baseline: 1.4605x; 1.0186x over previous
//
#include <hip/hip_runtime.h>

#define S_LEN 2048
#define DMODEL 1024
#define NH 16
#define DHD 64

typedef __attribute__((ext_vector_type(8))) short bh8;
typedef __attribute__((ext_vector_type(4))) float f32x4;
typedef __attribute__((ext_vector_type(2))) unsigned int u32x2;
typedef __attribute__((ext_vector_type(4))) unsigned int u32x4;
typedef unsigned short u16;
typedef unsigned int u32;

static __device__ __forceinline__ u16 f2bf(float f) {
    unsigned u = __builtin_bit_cast(unsigned, f);
    u += 0x7fffu + ((u >> 16) & 1u);
    return (u16)(u >> 16);
}

static __device__ __forceinline__ float bf2f(u16 v) {
    u32 u = ((u32)v) << 16;
    return __builtin_bit_cast(float, u);
}

typedef const __attribute__((address_space(1))) void* gptr_t;
typedef __attribute__((address_space(3))) void* lptr_t;

static __device__ __forceinline__ void gll16(const void* g, void* l) {
    __builtin_amdgcn_global_load_lds((gptr_t)g, (lptr_t)l, 16, 0, 0);
}

// ---------------- convert fp32 -> bf16: weights (4x1M) + sources (3x4M) --------------
__global__ __launch_bounds__(256) void cvt_all(const float* __restrict__ WQ, const float* __restrict__ WK,
                                               const float* __restrict__ WV, const float* __restrict__ WO,
                                               const float* __restrict__ S0, const float* __restrict__ S1,
                                               const float* __restrict__ S2,
                                               u16* __restrict__ wq, u16* __restrict__ wk,
                                               u16* __restrict__ wv, u16* __restrict__ wo,
                                               u16* __restrict__ q0, u16* __restrict__ k0,
                                               u16* __restrict__ v0) {
    int bid = blockIdx.x;
    const float* s;
    u16* o;
    size_t base;
    if (bid < 2048) {
        int wi = bid >> 9;
        s = wi == 0 ? WQ : (wi == 1 ? WK : (wi == 2 ? WV : WO));
        o = wi == 0 ? wq : (wi == 1 ? wk : (wi == 2 ? wv : wo));
        base = (size_t)(bid & 511) * 2048;
    } else {
        int r = bid - 2048;
        int si = r >> 11;
        s = si == 0 ? S0 : (si == 1 ? S1 : S2);
        o = si == 0 ? q0 : (si == 1 ? k0 : v0);
        base = (size_t)(r & 2047) * 2048;
    }
    size_t i = base + (size_t)threadIdx.x * 8;
    float4 a = *(const float4*)(s + i);
    float4 b = *(const float4*)(s + i + 4);
    u32 p0 = (u32)f2bf(a.x) | ((u32)f2bf(a.y) << 16);
    u32 p1 = (u32)f2bf(a.z) | ((u32)f2bf(a.w) << 16);
    u32 p2 = (u32)f2bf(b.x) | ((u32)f2bf(b.y) << 16);
    u32 p3 = (u32)f2bf(b.z) | ((u32)f2bf(b.w) << 16);
    *(u32x4*)(o + i) = (u32x4){p0, p1, p2, p3};
}

// ---------------- GEMM body: C[M,N] = A[M,K]*B[N,K]^T + bias, 2-phase dbuf ----------------
template <int BM, int OBF, int AF32>
static __device__ __forceinline__ void gemm_body(const void* __restrict__ Ap, const u16* __restrict__ Bm,
                                                 const float* __restrict__ bias, void* __restrict__ Cv,
                                                 int N, int K, int bi, int bj, short* Al, short* Bl,
                                                 float oscale) {
    constexpr int MI = BM / 32;
    constexpr int NC = BM / 64;
    int tid = threadIdx.x, lane = tid & 63, w = tid >> 6;
    int ln = lane & 15, hi = lane >> 4;
    int wm = w >> 1, wn = w & 1;
    f32x4 acc[MI][4];
#pragma unroll
    for (int i = 0; i < MI; i++)
#pragma unroll
        for (int j = 0; j < 4; j++) acc[i][j] = (f32x4){0.f, 0.f, 0.f, 0.f};
    int nk = K >> 5;

    float4 fa[NC][2];  // in-flight f32 A (AF32 path)
    auto loadA = [&](int kt) {
#pragma unroll
        for (int c = 0; c < NC; ++c) {
            int o = c * 4096 + tid * 16;
            int row = o >> 6, e0 = (o & 63) >> 1;
            const float* src = (const float*)Ap + (size_t)(bi * BM + row) * K + kt * 32 + e0;
            fa[c][0] = *(const float4*)src;
            fa[c][1] = *(const float4*)(src + 4);
        }
    };
    auto writeA = [&](int buf) {
#pragma unroll
        for (int c = 0; c < NC; ++c) {
            int o = c * 4096 + tid * 16;
            u32 w0 = (u32)f2bf(fa[c][0].x) | ((u32)f2bf(fa[c][0].y) << 16);
            u32 w1 = (u32)f2bf(fa[c][0].z) | ((u32)f2bf(fa[c][0].w) << 16);
            u32 w2 = (u32)f2bf(fa[c][1].x) | ((u32)f2bf(fa[c][1].y) << 16);
            u32 w3 = (u32)f2bf(fa[c][1].z) | ((u32)f2bf(fa[c][1].w) << 16);
            *(u32x4*)((char*)(Al + buf * (BM * 32)) + o) = (u32x4){w0, w1, w2, w3};
        }
    };
    auto stageA_lds = [&](int buf, int kt) {
#pragma unroll
        for (int c = 0; c < NC; ++c) {
            int o = c * 4096 + tid * 16;
            int row = o >> 6, col = (o & 63) >> 1;
            gll16((const u16*)Ap + (size_t)(bi * BM + row) * K + kt * 32 + col,
                  (char*)(Al + buf * (BM * 32)) + o);
        }
    };
    auto stageB = [&](int buf, int kt) {
#pragma unroll
        for (int c = 0; c < 2; ++c) {
            int o = c * 4096 + tid * 16;
            int row = o >> 6, col = (o & 63) >> 1;
            gll16(Bm + (size_t)(bj * 128 + row) * K + kt * 32 + col, (char*)(Bl + buf * 4096) + o);
        }
    };

    if constexpr (AF32) { loadA(0); writeA(0); } else { stageA_lds(0, 0); }
    stageB(0, 0);
    __syncthreads();
    int cur = 0;
    for (int kt = 0; kt < nk; ++kt) {
        bool pre = (kt + 1 < nk);
        if (pre) {
            if constexpr (AF32) loadA(kt + 1); else stageA_lds(cur ^ 1, kt + 1);
            stageB(cur ^ 1, kt + 1);
        }
        bh8 av[MI], bv[4];
#pragma unroll
        for (int i = 0; i < MI; i++) av[i] = *(const bh8*)&Al[cur * (BM * 32) + (wm * (BM / 2) + i * 16 + ln) * 32 + hi * 8];
#pragma unroll
        for (int j = 0; j < 4; j++) bv[j] = *(const bh8*)&Bl[cur * 4096 + (wn * 64 + j * 16 + ln) * 32 + hi * 8];
#pragma unroll
        for (int i = 0; i < MI; i++)
#pragma unroll
            for (int j = 0; j < 4; j++)
                acc[i][j] = __builtin_amdgcn_mfma_f32_16x16x32_bf16(av[i], bv[j], acc[i][j], 0, 0, 0);
        if constexpr (AF32) { if (pre) writeA(cur ^ 1); }
        __syncthreads();
        cur ^= 1;
    }
    if constexpr (OBF == 2) {
        // V projection: write C^T into VT[b,h,d,s] via LDS transpose (reuses Al+Bl = 32KB)
#pragma unroll
        for (int j = 0; j < 4; j++) {
            int col = wn * 64 + j * 16 + ln;  // local d_model col 0..127
            float bvs = bias[bj * 128 + col];
#pragma unroll
            for (int i = 0; i < MI; i++) {
                int row0 = wm * (BM / 2) + i * 16 + hi * 4;  // local s row
                u32 p01 = (u32)f2bf(acc[i][j][0] + bvs) | ((u32)f2bf(acc[i][j][1] + bvs) << 16);
                u32 p23 = (u32)f2bf(acc[i][j][2] + bvs) | ((u32)f2bf(acc[i][j][3] + bvs) << 16);
                int idx = col * 128 + (row0 ^ ((col & 7) << 3));
                *(u32x2*)&Al[idx] = (u32x2){p01, p23};
            }
        }
        __syncthreads();
        int b = bi >> 4;
        int sbase = (bi & 15) * 128;
#pragma unroll
        for (int it = 0; it < 8; ++it) {
            int idx = it * 256 + tid;
            int dcol = idx >> 4;           // 0..127
            int sl = (idx & 15) * 8;       // 0..120
            bh8 v = *(const bh8*)&Al[dcol * 128 + (sl ^ ((dcol & 7) << 3))];
            int h = bj * 2 + (dcol >> 6), d = dcol & 63;
            *(bh8*)((u16*)Cv + ((size_t)((b * 16 + h) * 64 + d)) * 2048 + sbase + sl) = v;
        }
        return;
    }
#pragma unroll
    for (int j = 0; j < 4; j++) {
        int col = bj * 128 + wn * 64 + j * 16 + ln;
        float bvs = bias[col];
#pragma unroll
        for (int i = 0; i < MI; i++) {
            int row0 = bi * BM + wm * (BM / 2) + i * 16 + hi * 4;
#pragma unroll
            for (int rr = 0; rr < 4; rr++) {
                if (OBF) {
                    float v = (acc[i][j][rr] + bvs) * oscale;  // Q-proj folds softmax scale here
                    ((u16*)Cv)[(size_t)(row0 + rr) * N + col] = f2bf(v);
                } else {
                    ((float*)Cv)[(size_t)(row0 + rr) * N + col] = acc[i][j][rr] + bvs;
                }
            }
        }
    }
}

// fused QKV projections, A pre-converted to bf16: grid 768 (XCD-swizzled); z==2 (V) writes VT
__global__ __launch_bounds__(256, 3) void gemm_qkv(const u16* __restrict__ A0, const u16* __restrict__ A1,
                                                   const u16* __restrict__ A2, const u16* __restrict__ B0,
                                                   const u16* __restrict__ B1, const u16* __restrict__ B2,
                                                   const float* __restrict__ c0, const float* __restrict__ c1,
                                                   const float* __restrict__ c2, u16* __restrict__ C0,
                                                   u16* __restrict__ C1, u16* __restrict__ VT) {
    __shared__ short SH[16384];  // 32KB: Al(16KB) + Bl(16KB); reused whole for V transpose
    short* Al = SH;
    short* Bl = SH + 8192;
    int bid = blockIdx.x;
    int swz = (bid & 7) * 96 + (bid >> 3);
    int z = swz >> 8, t = swz & 255;
    if (z == 2) {
        gemm_body<128, 2, 0>(A2, B2, c2, VT, 1024, 1024, t >> 3, t & 7, Al, Bl, 1.0f);
    } else if (z == 0) {
        gemm_body<128, 1, 0>(A0, B0, c0, C0, 1024, 1024, t >> 3, t & 7, Al, Bl, 0.18033688f);
    } else {
        gemm_body<128, 1, 0>(A1, B1, c1, C1, 1024, 1024, t >> 3, t & 7, Al, Bl, 1.0f);
    }
}

// ---------------- output projection + residual: 64x128 tile, K-SPLIT 8 waves -------------
// R13: Y2 intermediate in bf16 (halves write+read traffic) and residual read from the
// existing bf16 Qb copy (8MB vs 16MB f32). Stats/accum all stay f32.
__global__ __launch_bounds__(512, 4) void gemm_o(const u16* __restrict__ A, const u16* __restrict__ Bm,
                                                 const float* __restrict__ bias, const u16* __restrict__ Res,
                                                 u16* __restrict__ C) {
    __shared__ char SH[49152];           // Al 2x2x4KB (0..16K) + Bl 2x2x8KB (16K..48K)
    int tid = threadIdx.x, lane = tid & 63, w = tid >> 6;
    int ln = lane & 15, hi = lane >> 4;
    int kh = w >> 2;                     // k-half 0/1 (threads 0-255 / 256-511)
    int wq = w & 3;
    int wm = wq >> 1, wn = wq & 1;       // wave output 32 rows x 64 cols
    int tgl = tid & 255;
    int bid = blockIdx.x;
    int swz = (bid & 7) * 64 + (bid >> 3);
    int bi = swz >> 3, bj = swz & 7;
    f32x4 acc[2][4];
#pragma unroll
    for (int i = 0; i < 2; i++)
#pragma unroll
        for (int j = 0; j < 4; j++) acc[i][j] = (f32x4){0.f, 0.f, 0.f, 0.f};

    auto Alp = [&](int buf) { return (short*)(SH + kh * 8192 + buf * 4096); };
    auto Blp = [&](int buf) { return (short*)(SH + 16384 + kh * 16384 + buf * 8192); };
    auto stageA = [&](int buf, int kt) {
        int o = tgl * 16;                // 256 x 16B = 4KB = 64x32 bf16
        int row = o >> 6, col = (o & 63) >> 1;
        gll16(A + (size_t)(bi * 64 + row) * 1024 + kh * 512 + kt * 32 + col, (char*)Alp(buf) + o);
    };
    auto stageB = [&](int buf, int kt) {
#pragma unroll
        for (int c = 0; c < 2; ++c) {
            int o = c * 4096 + tgl * 16; // 8KB = 128x32 bf16
            int row = o >> 6, col = (o & 63) >> 1;
            gll16(Bm + (size_t)(bj * 128 + row) * 1024 + kh * 512 + kt * 32 + col, (char*)Blp(buf) + o);
        }
    };

    stageA(0, 0);
    stageB(0, 0);
    __syncthreads();
    int cur = 0;
    for (int kt = 0; kt < 16; ++kt) {
        if (kt + 1 < 16) {
            stageA(cur ^ 1, kt + 1);
            stageB(cur ^ 1, kt + 1);
        }
        bh8 av[2], bv[4];
#pragma unroll
        for (int i = 0; i < 2; i++) av[i] = *(const bh8*)&Alp(cur)[(wm * 32 + i * 16 + ln) * 32 + hi * 8];
#pragma unroll
        for (int j = 0; j < 4; j++) bv[j] = *(const bh8*)&Blp(cur)[(wn * 64 + j * 16 + ln) * 32 + hi * 8];
#pragma unroll
        for (int i = 0; i < 2; i++)
#pragma unroll
            for (int j = 0; j < 4; j++)
                acc[i][j] = __builtin_amdgcn_mfma_f32_16x16x32_bf16(av[i], bv[j], acc[i][j], 0, 0, 0);
        __syncthreads();
        cur ^= 1;
    }
    // ---- k-split combine: half-1 -> LDS (swizzled), barrier, half-0 finishes ----
    float* Csh = (float*)SH;             // 64x128 f32 = 32KB (staging dead)
    if (kh == 1) {
#pragma unroll
        for (int j = 0; j < 4; j++) {
            int col = wn * 64 + j * 16 + ln;
#pragma unroll
            for (int i = 0; i < 2; i++) {
                int r0 = wm * 32 + i * 16 + hi * 4;
                *(f32x4*)&Csh[col * 64 + (r0 ^ ((col & 7) << 2))] = acc[i][j];
            }
        }
    }
    __syncthreads();
    if (kh == 0) {
#pragma unroll
        for (int j = 0; j < 4; j++) {
            int col = wn * 64 + j * 16 + ln;
            int colg = bj * 128 + col;
            float bvs = bias[colg];
#pragma unroll
            for (int i = 0; i < 2; i++) {
                int r0 = wm * 32 + i * 16 + hi * 4;
                f32x4 p = *(const f32x4*)&Csh[col * 64 + (r0 ^ ((col & 7) << 2))];
#pragma unroll
                for (int rr = 0; rr < 4; rr++) {
                    size_t idx = (size_t)(bi * 64 + r0 + rr) * 1024 + colg;
                    C[idx] = f2bf(acc[i][j][rr] + p[rr] + bvs + bf2f(Res[idx]));
                }
            }
        }
    }
}

// ------- flash attention (causal): intra-block split-KV + 2-TILE UNROLL (R11, frozen) ----
template <int PLO, int PHI>
static __device__ __forceinline__ void attn_core(const u16* __restrict__ Qp, const u16* __restrict__ Kp,
                                                 const u16* __restrict__ VT, u16* __restrict__ Ctx,
                                                 short* Klb, short* Vlb, short* Pw, float* Csh, float* Ls,
                                                 int b, int h, int bh, int qt, int tid) {
    int lane = tid & 63, w = tid >> 6;       // w 0..7
    int grp = w >> 2;                        // kv chunk group
    int qsub = w & 3;                        // q-slot within group (32 rows each)
    int tgl = tid & 255;                     // thread id within group
    int ln = lane & 15, hi = lane >> 4;
    __builtin_amdgcn_s_setprio(PLO);
    bh8 ones;
#pragma unroll
    for (int e = 0; e < 8; e++) ones[e] = (short)0x3F80;  // bf16 1.0

    // per-group staging: Klb/Vlb point at this group's area (4 x 8KB buffers each)
    auto stage_kv = [&](int buf, int kt) {
#pragma unroll
        for (int c = 0; c < 2; ++c) {
            int o = c * 4096 + tgl * 16;     // 256 threads x 2 x 16B = 8KB per matrix
            int rr = o >> 7;
            int slot = (o >> 4) & 7;
            gll16(Kp + ((size_t)(b * S_LEN + kt * 64 + rr)) * DMODEL + h * DHD + ((slot ^ (rr & 7)) << 3),
                  (char*)(Klb + buf * 4096) + o);
            gll16(VT + ((size_t)(bh * DHD + rr)) * S_LEN + kt * 64 + ((slot ^ (rr & 7)) << 3),
                  (char*)(Vlb + buf * 4096) + o);
        }
    };

    int nh = qt + 1;                         // tiles per group
    int nt = 2 * qt + 2;                     // total causal kv tiles
    int kbase = grp * nh;
    int qg0 = (qt << 7) + qsub * 32 + ln;    // q-group 0 row; group 1 = qg0 + 16
    const bh8* qr0 = (const bh8*)(Qp + ((size_t)(b * S_LEN + qg0)) * DMODEL + h * DHD);
    const bh8* qr1 = (const bh8*)(Qp + ((size_t)(b * S_LEN + qg0 + 16)) * DMODEL + h * DHD);
    bh8 qf[2][2];
    qf[0][0] = qr0[hi]; qf[0][1] = qr0[4 + hi];
    qf[1][0] = qr1[hi]; qf[1][1] = qr1[4 + hi];
    f32x4 ctxa[2][4];
    f32x4 lacc[2];
#pragma unroll
    for (int g = 0; g < 2; g++) {
        lacc[g] = (f32x4){0.f, 0.f, 0.f, 0.f};
#pragma unroll
        for (int i = 0; i < 4; i++) ctxa[g][i] = (f32x4){0.f, 0.f, 0.f, 0.f};
    }
    stage_kv(0, kbase);
    if (nh > 1) stage_kv(1, kbase + 1);
    __syncthreads();
    for (int i = 0; i < nh; i += 2) {
        int s = i >> 1;
        int b0 = (s & 1) << 1;               // buffer pair {0,1} / {2,3} alternating
        int b1 = b0 + 1;
        bool two = (i + 1 < nh);
        if (i + 2 < nh) stage_kv(b0 ^ 2, kbase + i + 2);
        if (i + 3 < nh) stage_kv(b1 ^ 2, kbase + i + 3);
        int kt0 = kbase + i;
        int kt1 = kbase + i + 1;
        f32x4 scA[2][4], scB[2][4];
#pragma unroll
        for (int g = 0; g < 2; g++)
#pragma unroll
            for (int ks = 0; ks < 4; ++ks) { scA[g][ks] = (f32x4){0.f, 0.f, 0.f, 0.f}; scB[g][ks] = (f32x4){0.f, 0.f, 0.f, 0.f}; }
        // QK for both tiles first: QK(t1) MFMAs can issue while SM(t0) runs on VALU
        __builtin_amdgcn_s_setprio(PHI);
#pragma unroll
        for (int dwin = 0; dwin < 2; ++dwin) {
#pragma unroll
            for (int ks = 0; ks < 4; ++ks) {
                int rr = ks * 16 + ln;
                bh8 kv = *(const bh8*)&Klb[b0 * 4096 + rr * 64 + ((dwin * 32 + hi * 8) ^ ((rr & 7) << 3))];
                scA[0][ks] = __builtin_amdgcn_mfma_f32_16x16x32_bf16(kv, qf[0][dwin], scA[0][ks], 0, 0, 0);
                scA[1][ks] = __builtin_amdgcn_mfma_f32_16x16x32_bf16(kv, qf[1][dwin], scA[1][ks], 0, 0, 0);
            }
        }
        if (two) {
#pragma unroll
            for (int dwin = 0; dwin < 2; ++dwin) {
#pragma unroll
                for (int ks = 0; ks < 4; ++ks) {
                    int rr = ks * 16 + ln;
                    bh8 kv = *(const bh8*)&Klb[b1 * 4096 + rr * 64 + ((dwin * 32 + hi * 8) ^ ((rr & 7) << 3))];
                    scB[0][ks] = __builtin_amdgcn_mfma_f32_16x16x32_bf16(kv, qf[0][dwin], scB[0][ks], 0, 0, 0);
                    scB[1][ks] = __builtin_amdgcn_mfma_f32_16x16x32_bf16(kv, qf[1][dwin], scB[1][ks], 0, 0, 0);
                }
            }
        }
        __builtin_amdgcn_s_setprio(PLO);
        if (kt0 >= nt - 2) {
#pragma unroll
            for (int g = 0; g < 2; g++) {
                int qgq = qg0 + g * 16;
#pragma unroll
                for (int ks = 0; ks < 4; ++ks)
#pragma unroll
                    for (int rr = 0; rr < 4; ++rr) {
                        int kg = kt0 * 64 + ks * 16 + hi * 4 + rr;
                        scA[g][ks][rr] = (kg <= qgq) ? scA[g][ks][rr] : -1e30f;
                    }
            }
        }
        // ---- tile 0: softmax -> P -> PV ----
#pragma unroll
        for (int g = 0; g < 2; g++) {
#pragma unroll
            for (int ks = 0; ks < 4; ++ks) {
                u32 u0 = __builtin_bit_cast(u32, __builtin_amdgcn_exp2f(scA[g][ks][0]));
                u32 u1 = __builtin_bit_cast(u32, __builtin_amdgcn_exp2f(scA[g][ks][1]));
                u32 u2 = __builtin_bit_cast(u32, __builtin_amdgcn_exp2f(scA[g][ks][2]));
                u32 u3 = __builtin_bit_cast(u32, __builtin_amdgcn_exp2f(scA[g][ks][3]));
                u32 a01 = (u0 >> 16) | (u1 & 0xffff0000u);   // truncating bf16 pack
                u32 a23 = (u2 >> 16) | (u3 & 0xffff0000u);
                int kloc = ks * 16 + hi * 4;
                *(u32x2*)&Pw[(g * 16 + ln) * 64 + (kloc ^ ((ln & 7) << 3))] = (u32x2){a01, a23};
            }
        }
        __builtin_amdgcn_s_setprio(PHI);
#pragma unroll
        for (int kw = 0; kw < 2; ++kw) {
            bh8 pf0 = *(const bh8*)&Pw[ln * 64 + ((kw * 32 + hi * 8) ^ ((ln & 7) << 3))];
            bh8 pf1 = *(const bh8*)&Pw[(16 + ln) * 64 + ((kw * 32 + hi * 8) ^ ((ln & 7) << 3))];
            lacc[0] = __builtin_amdgcn_mfma_f32_16x16x32_bf16(ones, pf0, lacc[0], 0, 0, 0);
            lacc[1] = __builtin_amdgcn_mfma_f32_16x16x32_bf16(ones, pf1, lacc[1], 0, 0, 0);
#pragma unroll
            for (int ds = 0; ds < 4; ++ds) {
                int d = ds * 16 + ln;
                bh8 vf = *(const bh8*)&Vlb[b0 * 4096 + d * 64 + ((kw * 32 + hi * 8) ^ ((d & 7) << 3))];
                ctxa[0][ds] = __builtin_amdgcn_mfma_f32_16x16x32_bf16(vf, pf0, ctxa[0][ds], 0, 0, 0);
                ctxa[1][ds] = __builtin_amdgcn_mfma_f32_16x16x32_bf16(vf, pf1, ctxa[1][ds], 0, 0, 0);
            }
        }
        __builtin_amdgcn_s_setprio(PLO);
        // ---- tile 1: softmax -> P -> PV (in-order DS: PV(t0) reads retire first) ----
        if (two) {
            if (kt1 >= nt - 2) {
#pragma unroll
                for (int g = 0; g < 2; g++) {
                    int qgq = qg0 + g * 16;
#pragma unroll
                    for (int ks = 0; ks < 4; ++ks)
#pragma unroll
                        for (int rr = 0; rr < 4; ++rr) {
                            int kg = kt1 * 64 + ks * 16 + hi * 4 + rr;
                            scB[g][ks][rr] = (kg <= qgq) ? scB[g][ks][rr] : -1e30f;
                        }
                }
            }
#pragma unroll
            for (int g = 0; g < 2; g++) {
#pragma unroll
                for (int ks = 0; ks < 4; ++ks) {
                    u32 u0 = __builtin_bit_cast(u32, __builtin_amdgcn_exp2f(scB[g][ks][0]));
                    u32 u1 = __builtin_bit_cast(u32, __builtin_amdgcn_exp2f(scB[g][ks][1]));
                    u32 u2 = __builtin_bit_cast(u32, __builtin_amdgcn_exp2f(scB[g][ks][2]));
                    u32 u3 = __builtin_bit_cast(u32, __builtin_amdgcn_exp2f(scB[g][ks][3]));
                    u32 a01 = (u0 >> 16) | (u1 & 0xffff0000u);
                    u32 a23 = (u2 >> 16) | (u3 & 0xffff0000u);
                    int kloc = ks * 16 + hi * 4;
                    *(u32x2*)&Pw[(g * 16 + ln) * 64 + (kloc ^ ((ln & 7) << 3))] = (u32x2){a01, a23};
                }
            }
            __builtin_amdgcn_s_setprio(PHI);
#pragma unroll
            for (int kw = 0; kw < 2; ++kw) {
                bh8 pf0 = *(const bh8*)&Pw[ln * 64 + ((kw * 32 + hi * 8) ^ ((ln & 7) << 3))];
                bh8 pf1 = *(const bh8*)&Pw[(16 + ln) * 64 + ((kw * 32 + hi * 8) ^ ((ln & 7) << 3))];
                lacc[0] = __builtin_amdgcn_mfma_f32_16x16x32_bf16(ones, pf0, lacc[0], 0, 0, 0);
                lacc[1] = __builtin_amdgcn_mfma_f32_16x16x32_bf16(ones, pf1, lacc[1], 0, 0, 0);
#pragma unroll
                for (int ds = 0; ds < 4; ++ds) {
                    int d = ds * 16 + ln;
                    bh8 vf = *(const bh8*)&Vlb[b1 * 4096 + d * 64 + ((kw * 32 + hi * 8) ^ ((d & 7) << 3))];
                    ctxa[0][ds] = __builtin_amdgcn_mfma_f32_16x16x32_bf16(vf, pf0, ctxa[0][ds], 0, 0, 0);
                    ctxa[1][ds] = __builtin_amdgcn_mfma_f32_16x16x32_bf16(vf, pf1, ctxa[1][ds], 0, 0, 0);
                }
            }
            __builtin_amdgcn_s_setprio(PLO);
        }
        __syncthreads();
    }
    __builtin_amdgcn_s_setprio(0);
    // ---- intra-block combine: grp1 -> LDS, barrier, grp0 adds + normalizes + writes ----
    if (grp == 1) {
#pragma unroll
        for (int g = 0; g < 2; g++) {
            int qloc = g * 16 + ln;
#pragma unroll
            for (int ds = 0; ds < 4; ++ds) {
                int doff = (ds * 16 + hi * 4) ^ ((qloc & 7) << 3);  // bank-spread swizzle
                *(f32x4*)&Csh[(qsub * 32 + qloc) * 64 + doff] = ctxa[g][ds];
            }
            if (hi == 0) Ls[qsub * 32 + qloc] = lacc[g][0];
        }
    }
    __syncthreads();
    if (grp == 0) {
#pragma unroll
        for (int g = 0; g < 2; g++) {
            int qloc = g * 16 + ln;
            float inv = 1.f / (lacc[g][0] + Ls[qsub * 32 + qloc]);
            u16* cp = Ctx + ((size_t)(b * S_LEN + qg0 + g * 16)) * DMODEL + h * DHD;
#pragma unroll
            for (int ds = 0; ds < 4; ++ds) {
                int doff = (ds * 16 + hi * 4) ^ ((qloc & 7) << 3);
                f32x4 p = *(const f32x4*)&Csh[(qsub * 32 + qloc) * 64 + doff];
                ushort4 st;
                st.x = f2bf((ctxa[g][ds][0] + p[0]) * inv);
                st.y = f2bf((ctxa[g][ds][1] + p[1]) * inv);
                st.z = f2bf((ctxa[g][ds][2] + p[2]) * inv);
                st.w = f2bf((ctxa[g][ds][3] + p[3]) * inv);
                *(ushort4*)(cp + ds * 16 + hi * 4) = st;
            }
        }
    }
}

__global__ __launch_bounds__(512, 1) void attn_fwd(const u16* __restrict__ Qp, const u16* __restrict__ Kp,
                                                   const u16* __restrict__ VT, u16* __restrict__ Ctx) {
    __shared__ short Kl[2][4][4096];   // [grp][buf] 64KB
    __shared__ short Vl[2][4][4096];   // 64KB
    __shared__ short Pl[8][2048];      // per-wave 32x64 P, 32KB  (total = 160KB exactly)
    int tid = threadIdx.x, w = tid >> 6;
    int grp = w >> 2;
    int bid = blockIdx.x;
    int rnd = bid >> 8, slot = bid & 255;
    int xcd = slot & 7, t = slot >> 3;       // t 0..31
    int bh = xcd * 4 + (t & 3);              // bh pinned to XCD both rounds (K/V L2)
    int qte = t >> 2;                        // 0..7
    int qt = rnd ? (15 - 2 * qte) : (2 * qte);  // rnd0: evens asc; rnd1: odds desc (greedy pairing)
    int b = bh >> 4, h = bh & 15;
    float* Csh = (float*)&Kl[0][0][0];       // 32KB combine buffer (staging dead by then)
    float* Ls = (float*)&Pl[7][1024];        // 512B l-partials in grp1's dead P region
    if (qt >= 8)
        attn_core<2, 3>(Qp, Kp, VT, Ctx, &Kl[grp][0][0], &Vl[grp][0][0], &Pl[w][0], Csh, Ls, b, h, bh, qt, tid);
    else
        attn_core<0, 1>(Qp, Kp, VT, Ctx, &Kl[grp][0][0], &Vl[grp][0][0], &Pl[w][0], Csh, Ls, b, h, bh, qt, tid);
}

// ---------------- LayerNorm (bf16 input already includes residual, from gemm_o) ----------
__global__ __launch_bounds__(256) void ln_res(const u16* __restrict__ Y,
                                              const float* __restrict__ gamma, const float* __restrict__ beta,
                                              float* __restrict__ out) {
    int row = blockIdx.x, tid = threadIdx.x;
    ushort4 a = *(const ushort4*)(Y + (size_t)row * DMODEL + tid * 4);
    float x0 = bf2f(a.x), x1 = bf2f(a.y), x2 = bf2f(a.z), x3 = bf2f(a.w);
    float s1 = x0 + x1 + x2 + x3;
    float s2 = x0 * x0 + x1 * x1 + x2 * x2 + x3 * x3;
#pragma unroll
    for (int off = 32; off > 0; off >>= 1) {
        s1 += __shfl_xor(s1, off);
        s2 += __shfl_xor(s2, off);
    }
    __shared__ float r1[4], r2[4];
    int wv = tid >> 6;
    if ((tid & 63) == 0) { r1[wv] = s1; r2[wv] = s2; }
    __syncthreads();
    s1 = r1[0] + r1[1] + r1[2] + r1[3];
    s2 = r2[0] + r2[1] + r2[2] + r2[3];
    float mu = s1 * (1.0f / 1024.0f);
    float var = s2 * (1.0f / 1024.0f) - mu * mu;
    float rstd = rsqrtf(var + 1e-5f);
    const float4* g4 = (const float4*)gamma;
    const float4* b4 = (const float4*)beta;
    float4 g = g4[tid], bb = b4[tid];
    float4 res;
    res.x = (x0 - mu) * rstd * g.x + bb.x;
    res.y = (x1 - mu) * rstd * g.y + bb.y;
    res.z = (x2 - mu) * rstd * g.z + bb.z;
    res.w = (x3 - mu) * rstd * g.w + bb.w;
    *((float4*)(out + (size_t)row * DMODEL) + tid) = res;
}

extern "C" void kernel_launch(void* const* d_in, const int* in_sizes, int n_in,
                              void* d_out, int out_size, void* d_ws, size_t ws_size,
                              hipStream_t stream) {
    const float* Qs = (const float*)d_in[0];
    const float* Ks = (const float*)d_in[1];
    const float* Vs = (const float*)d_in[2];
    const float* WQ = (const float*)d_in[5];
    const float* bQ = (const float*)d_in[6];
    const float* WK = (const float*)d_in[7];
    const float* bK = (const float*)d_in[8];
    const float* WV = (const float*)d_in[9];
    const float* bV = (const float*)d_in[10];
    const float* WO = (const float*)d_in[11];
    const float* bO = (const float*)d_in[12];
    const float* gamma = (const float*)d_in[13];
    const float* beta = (const float*)d_in[14];

    const size_t MB = 1u << 20;
    char* w8 = (char*)d_ws;
    u16* Qb  = (u16*)(w8 + 0 * MB);   // bf16 sources (8MB each)
    u16* Kb  = (u16*)(w8 + 8 * MB);
    u16* Vb  = (u16*)(w8 + 16 * MB);
    u16* WQb = (u16*)(w8 + 24 * MB);
    u16* WKb = (u16*)(w8 + 26 * MB);
    u16* WVb = (u16*)(w8 + 28 * MB);
    u16* WOb = (u16*)(w8 + 30 * MB);
    u16* Qp  = (u16*)(w8 + 32 * MB);
    u16* Kp  = (u16*)(w8 + 40 * MB);
    u16* VTb = (u16*)(w8 + 56 * MB);
    u16* Ctx = (u16*)(w8 + 64 * MB);
    u16* Y2b = (u16*)(w8 + 72 * MB);  // bf16 Y2 (8MB)

    cvt_all<<<8192, 256, 0, stream>>>(WQ, WK, WV, WO, Qs, Ks, Vs, WQb, WKb, WVb, WOb, Qb, Kb, Vb);
    gemm_qkv<<<768, 256, 0, stream>>>(Qb, Kb, Vb, WQb, WKb, WVb, bQ, bK, bV, Qp, Kp, VTb);
    attn_fwd<<<512, 512, 0, stream>>>(Qp, Kp, VTb, Ctx);
    gemm_o<<<512, 512, 0, stream>>>(Ctx, WOb, bO, Qb, Y2b);
    ln_res<<<4096, 256, 0, stream>>>(Y2b, gamma, beta, (float*)d_out);
}